// Round 3
// baseline (4122.793 us; speedup 1.0000x reference)
//
#include <hip/hip_runtime.h>
#include <hip/hip_bf16.h>

typedef __hip_bfloat16 bf16;

static constexpr int N_NODES  = 50000;
static constexpr int N_EDGES  = 800000;
static constexpr int F_IN     = 128;
static constexpr int D_HID    = 128;
static constexpr int H_HEADS  = 3;
static constexpr int F_OUT    = 40;
static constexpr float BN_EPS = 1e-5f;
static constexpr float SLOPE  = 0.2f;

// ---------------- GEMM: C[M,Nc] = A[M,K] @ W[K,Nc] (fp32 in, bf16 out) ------
__global__ void gemm_kernel(const float* __restrict__ A, const float* __restrict__ W,
                            bf16* __restrict__ C, int M, int K, int Nc) {
  __shared__ float As[16][17];
  __shared__ float Ws[16][17];
  int tx = threadIdx.x, ty = threadIdx.y;
  int row = blockIdx.y * 16 + ty;
  int col = blockIdx.x * 16 + tx;
  float acc = 0.f;
  for (int k0 = 0; k0 < K; k0 += 16) {
    As[ty][tx] = (row < M) ? A[(size_t)row * K + k0 + tx] : 0.f;
    Ws[ty][tx] = (col < Nc) ? W[(size_t)(k0 + ty) * Nc + col] : 0.f;
    __syncthreads();
#pragma unroll
    for (int kk = 0; kk < 16; ++kk) acc += As[ty][kk] * Ws[kk][tx];
    __syncthreads();
  }
  if (row < M && col < Nc) C[(size_t)row * Nc + col] = __float2bfloat16(acc);
}

// ------------- el/er: per (node,head) dot(f[n,h,:], al[h,:]) ----------------
__global__ void el_er_kernel(const bf16* __restrict__ f, const float* __restrict__ al,
                             const float* __restrict__ ar, float* __restrict__ el,
                             float* __restrict__ er, int N, int H, int D) {
  int gtid = blockIdx.x * blockDim.x + threadIdx.x;
  int wave = gtid >> 6, lane = gtid & 63;
  if (wave >= N * H) return;
  int h = wave % H;
  const bf16* frow = f + (size_t)wave * D;
  float sl = 0.f, sr = 0.f;
  for (int d = lane; d < D; d += 64) {
    float v = __bfloat162float(frow[d]);
    sl += v * al[h * D + d];
    sr += v * ar[h * D + d];
  }
#pragma unroll
  for (int off = 32; off > 0; off >>= 1) {
    sl += __shfl_down(sl, off);
    sr += __shfl_down(sr, off);
  }
  if (lane == 0) { el[wave] = sl; er[wave] = sr; }
}

// ------------- edge pass 1: leaky score + segment max (encoded atomicMax) ---
__global__ void edge_score_kernel(const int* __restrict__ src, const int* __restrict__ dst,
                                  const float* __restrict__ el, const float* __restrict__ er,
                                  float* __restrict__ sc, unsigned int* __restrict__ menc,
                                  int E, int H) {
  int i = blockIdx.x * blockDim.x + threadIdx.x;
  if (i >= E * H) return;
  int e = i / H, h = i - e * H;
  int s = src[e], d = dst[e];
  float v = el[s * H + h] + er[d * H + h];
  v = v > 0.f ? v : SLOPE * v;
  sc[i] = v;
  unsigned int u = __float_as_uint(v);
  u = (u & 0x80000000u) ? ~u : (u | 0x80000000u);
  atomicMax(menc + d * H + h, u);
}

// ------------- edge pass 2: ex = exp(sc - m[dst]); segment sum --------------
__global__ void edge_exp_kernel(const int* __restrict__ dst, float* __restrict__ sc,
                                const unsigned int* __restrict__ menc,
                                float* __restrict__ ssum, int E, int H) {
  int i = blockIdx.x * blockDim.x + threadIdx.x;
  if (i >= E * H) return;
  int e = i / H, h = i - e * H;
  int d = dst[e];
  unsigned int u = menc[d * H + h];
  float m = (u & 0x80000000u) ? __uint_as_float(u ^ 0x80000000u) : __uint_as_float(~u);
  float ex = __expf(sc[i] - m);
  sc[i] = ex;
  atomicAdd(ssum + d * H + h, ex);
}

// ------------- edge pass 3: out[dst] += f[src] * a  (atomic scatter) --------
__global__ void edge_aggr_kernel(const int* __restrict__ src, const int* __restrict__ dst,
                                 const bf16* __restrict__ f, const float* __restrict__ ex,
                                 const float* __restrict__ ssum, float* __restrict__ out,
                                 int E, int H, int D) {
  int e = blockIdx.x;
  if (e >= E) return;
  int s = src[e], d = dst[e];
  for (int h = 0; h < H; ++h) {
    float a = ex[(size_t)e * H + h] / ssum[d * H + h];
    for (int j = threadIdx.x; j < D; j += blockDim.x) {
      float v = __bfloat162float(f[((size_t)s * H + h) * D + j]) * a;
      atomicAdd(out + ((size_t)d * H + h) * D + j, v);
    }
  }
}

// ------------- BN stats: per-channel sum / sumsq ----------------------------
__global__ void bn_stats_kernel(const float* __restrict__ h, float* __restrict__ sum,
                                float* __restrict__ sumsq, int N, int C) {
  int c = threadIdx.x;  // blockDim.x == C
  float s = 0.f, s2 = 0.f;
  for (int n = blockIdx.x; n < N; n += gridDim.x) {
    float v = h[(size_t)n * C + c];
    s += v; s2 += v * v;
  }
  atomicAdd(sum + c, s);
  atomicAdd(sumsq + c, s2);
}

// ------------- BN apply + ReLU (in place) -----------------------------------
__global__ void bn_apply_kernel(float* __restrict__ h, const float* __restrict__ sum,
                                const float* __restrict__ sumsq, const float* __restrict__ g,
                                const float* __restrict__ be, int N, int C) {
  int i = blockIdx.x * blockDim.x + threadIdx.x;
  if (i >= N * C) return;
  int c = i % C;
  float inv_n = 1.f / (float)N;
  float mu = sum[c] * inv_n;
  float var = sumsq[c] * inv_n - mu * mu;
  float v = (h[i] - mu) * rsqrtf(var + BN_EPS) * g[c] + be[c];
  h[i] = v > 0.f ? v : 0.f;
}

// ------------- final: add bias, fp32 output ---------------------------------
__global__ void final_kernel(const float* __restrict__ o, const float* __restrict__ b,
                             float* __restrict__ out, int N, int C) {
  int i = blockIdx.x * blockDim.x + threadIdx.x;
  if (i >= N * C) return;
  int c = i % C;
  out[i] = o[i] + b[c];
}

static inline int cdiv(int a, int b) { return (a + b - 1) / b; }

extern "C" void kernel_launch(void* const* d_in, const int* in_sizes, int n_in,
                              void* d_out, int out_size, void* d_ws, size_t ws_size,
                              hipStream_t stream) {
  const float* x   = (const float*)d_in[0];
  const int* src   = (const int*)d_in[1];
  const int* dst   = (const int*)d_in[2];
  const float* W0  = (const float*)d_in[3];
  const float* al0 = (const float*)d_in[4];
  const float* ar0 = (const float*)d_in[5];
  // b0 = d_in[6] : zeros, and would cancel under BN anyway
  const float* W1  = (const float*)d_in[7];
  const float* al1 = (const float*)d_in[8];
  const float* ar1 = (const float*)d_in[9];
  // b1 = d_in[10] : zeros, cancels under BN
  const float* W2  = (const float*)d_in[11];
  const float* al2 = (const float*)d_in[12];
  const float* ar2 = (const float*)d_in[13];
  const float* b2  = (const float*)d_in[14];
  const float* g0  = (const float*)d_in[15];
  const float* be0 = (const float*)d_in[16];
  const float* g1  = (const float*)d_in[17];
  const float* be1 = (const float*)d_in[18];
  float* out = (float*)d_out;   // reference output dtype is float32

  const int N = N_NODES, E = N_EDGES, H = H_HEADS, D = D_HID;
  const int C = H * D;  // 384

  // ---- workspace carve (~136 MB total) ----
  char* p = (char*)d_ws;
  auto take = [&](size_t bytes) {
    char* r = p;
    p += (bytes + 255) & ~(size_t)255;
    return r;
  };
  bf16*  f_buf = (bf16*) take((size_t)N * C * sizeof(bf16));   // fc output (all layers)
  float* hbuf  = (float*)take((size_t)N * C * sizeof(float));  // aggregated node features (reused per layer)
  float* exb   = (float*)take((size_t)E * H * sizeof(float));  // edge scores / exp
  float* el    = (float*)take((size_t)N * H * sizeof(float));
  float* er    = (float*)take((size_t)N * H * sizeof(float));
  unsigned int* menc = (unsigned int*)take((size_t)N * H * sizeof(unsigned int));
  float* ssum  = (float*)take((size_t)N * H * sizeof(float));
  float* bnsum = (float*)take((size_t)C * sizeof(float));
  float* bnsq  = (float*)take((size_t)C * sizeof(float));
  float* out2  = (float*)take((size_t)N * F_OUT * sizeof(float));

  const dim3 tb16(16, 16);

  // ================= layer 0: x[N,128] -> hbuf[N,384] =================
  gemm_kernel<<<dim3(cdiv(C, 16), cdiv(N, 16)), tb16, 0, stream>>>(x, W0, f_buf, N, F_IN, C);
  hipMemsetAsync(hbuf, 0, (size_t)N * C * sizeof(float), stream);
  hipMemsetAsync(menc, 0, (size_t)N * H * sizeof(unsigned int), stream);
  hipMemsetAsync(ssum, 0, (size_t)N * H * sizeof(float), stream);
  hipMemsetAsync(bnsum, 0, C * sizeof(float), stream);
  hipMemsetAsync(bnsq,  0, C * sizeof(float), stream);
  el_er_kernel<<<cdiv(N * H * 64, 256), 256, 0, stream>>>(f_buf, al0, ar0, el, er, N, H, D);
  edge_score_kernel<<<cdiv(E * H, 256), 256, 0, stream>>>(src, dst, el, er, exb, menc, E, H);
  edge_exp_kernel<<<cdiv(E * H, 256), 256, 0, stream>>>(dst, exb, menc, ssum, E, H);
  edge_aggr_kernel<<<E, 128, 0, stream>>>(src, dst, f_buf, exb, ssum, hbuf, E, H, D);
  bn_stats_kernel<<<256, C, 0, stream>>>(hbuf, bnsum, bnsq, N, C);
  bn_apply_kernel<<<cdiv(N * C, 256), 256, 0, stream>>>(hbuf, bnsum, bnsq, g0, be0, N, C);

  // ================= layer 1: hbuf[N,384] -> hbuf[N,384] =================
  gemm_kernel<<<dim3(cdiv(C, 16), cdiv(N, 16)), tb16, 0, stream>>>(hbuf, W1, f_buf, N, C, C);
  hipMemsetAsync(hbuf, 0, (size_t)N * C * sizeof(float), stream);  // dead after gemm
  hipMemsetAsync(menc, 0, (size_t)N * H * sizeof(unsigned int), stream);
  hipMemsetAsync(ssum, 0, (size_t)N * H * sizeof(float), stream);
  hipMemsetAsync(bnsum, 0, C * sizeof(float), stream);
  hipMemsetAsync(bnsq,  0, C * sizeof(float), stream);
  el_er_kernel<<<cdiv(N * H * 64, 256), 256, 0, stream>>>(f_buf, al1, ar1, el, er, N, H, D);
  edge_score_kernel<<<cdiv(E * H, 256), 256, 0, stream>>>(src, dst, el, er, exb, menc, E, H);
  edge_exp_kernel<<<cdiv(E * H, 256), 256, 0, stream>>>(dst, exb, menc, ssum, E, H);
  edge_aggr_kernel<<<E, 128, 0, stream>>>(src, dst, f_buf, exb, ssum, hbuf, E, H, D);
  bn_stats_kernel<<<256, C, 0, stream>>>(hbuf, bnsum, bnsq, N, C);
  bn_apply_kernel<<<cdiv(N * C, 256), 256, 0, stream>>>(hbuf, bnsum, bnsq, g1, be1, N, C);

  // ================= layer 2: hbuf[N,384] -> out[N,40], 1 head =================
  gemm_kernel<<<dim3(cdiv(F_OUT, 16), cdiv(N, 16)), tb16, 0, stream>>>(hbuf, W2, f_buf, N, C, F_OUT);
  hipMemsetAsync(out2, 0, (size_t)N * F_OUT * sizeof(float), stream);
  hipMemsetAsync(menc, 0, (size_t)N * sizeof(unsigned int), stream);
  hipMemsetAsync(ssum, 0, (size_t)N * sizeof(float), stream);
  el_er_kernel<<<cdiv(N * 64, 256), 256, 0, stream>>>(f_buf, al2, ar2, el, er, N, 1, F_OUT);
  edge_score_kernel<<<cdiv(E, 256), 256, 0, stream>>>(src, dst, el, er, exb, menc, E, 1);
  edge_exp_kernel<<<cdiv(E, 256), 256, 0, stream>>>(dst, exb, menc, ssum, E, 1);
  edge_aggr_kernel<<<E, 64, 0, stream>>>(src, dst, f_buf, exb, ssum, out2, E, 1, F_OUT);
  final_kernel<<<cdiv(N * F_OUT, 256), 256, 0, stream>>>(out2, b2, out, N, F_OUT);
}

// Round 4
// 2805.013 us; speedup vs baseline: 1.4698x; 1.4698x over previous
//
#include <hip/hip_runtime.h>
#include <hip/hip_bf16.h>

typedef __hip_bfloat16 bf16;
typedef __attribute__((ext_vector_type(8))) short short8;
typedef __attribute__((ext_vector_type(4))) float f32x4;

static constexpr int N_NODES  = 50000;
static constexpr int N_EDGES  = 800000;
static constexpr int F_IN     = 128;
static constexpr int D_HID    = 128;
static constexpr int H_HEADS  = 3;
static constexpr int F_OUT    = 40;
static constexpr float BN_EPS = 1e-5f;
static constexpr float SLOPE  = 0.2f;

__device__ __forceinline__ float bf2f(short s) {
  return __uint_as_float(((unsigned int)(unsigned short)s) << 16);
}

// ---------------- MFMA GEMM: C[M,Nc] = A[M,K] @ WT[Nc,K]^T, bf16 in, bf16 out
// A row-major [M,K] bf16; WT row-major [Ncpad,K] bf16 (rows >= Nc are zero).
// Tile: 64x64, 4 waves, BK=64, fp32 accum.
__global__ __launch_bounds__(256) void gemm_mfma(const short* __restrict__ A,
                                                 const short* __restrict__ WT,
                                                 bf16* __restrict__ C,
                                                 int M, int K, int Nc) {
  constexpr int BM = 64, BN = 64, BK = 64, LDP = BK + 8;  // +8 shorts pad
  __shared__ short As[BM * LDP];
  __shared__ short Bs[BN * LDP];
  int tid = threadIdx.x;
  int wave = tid >> 6, lane = tid & 63;
  int bm = blockIdx.y, bn = blockIdx.x;

  int lrow = tid >> 3;          // 0..31 (chunk row base)
  int kcol = (tid & 7) * 8;     // 0,8,...,56

  f32x4 acc[4];
#pragma unroll
  for (int i = 0; i < 4; ++i) acc[i] = (f32x4){0.f, 0.f, 0.f, 0.f};

  int m15 = lane & 15;
  int ksub = (lane >> 4) * 8;

  for (int k0 = 0; k0 < K; k0 += BK) {
#pragma unroll
    for (int c = 0; c < 2; ++c) {
      int r = lrow + c * 32;
      int gr = bm * BM + r; if (gr >= M) gr = M - 1;       // clamp; stores guarded
      *(short8*)&As[r * LDP + kcol] = *(const short8*)&A[(size_t)gr * K + k0 + kcol];
      int gn = bn * BN + r;                                 // WT padded: always valid
      *(short8*)&Bs[r * LDP + kcol] = *(const short8*)&WT[(size_t)gn * K + k0 + kcol];
    }
    __syncthreads();
#pragma unroll
    for (int ks = 0; ks < BK; ks += 32) {
      short8 a = *(const short8*)&As[(wave * 16 + m15) * LDP + ks + ksub];
#pragma unroll
      for (int nb = 0; nb < 4; ++nb) {
        short8 b = *(const short8*)&Bs[(nb * 16 + m15) * LDP + ks + ksub];
        acc[nb] = __builtin_amdgcn_mfma_f32_16x16x32_bf16(a, b, acc[nb], 0, 0, 0);
      }
    }
    __syncthreads();
  }
  // C/D layout: col = lane&15, row = (lane>>4)*4 + r
#pragma unroll
  for (int nb = 0; nb < 4; ++nb) {
    int col = bn * BN + nb * 16 + m15;
#pragma unroll
    for (int r = 0; r < 4; ++r) {
      int row = bm * BM + wave * 16 + (lane >> 4) * 4 + r;
      if (row < M && col < Nc)
        C[(size_t)row * Nc + col] = __float2bfloat16(acc[nb][r]);
    }
  }
}

// ------------- cast fp32 -> bf16 (grid-stride) ------------------------------
__global__ void cast_bf16_kernel(const float* __restrict__ in, bf16* __restrict__ out, int n) {
  for (int i = blockIdx.x * blockDim.x + threadIdx.x; i < n; i += gridDim.x * blockDim.x)
    out[i] = __float2bfloat16(in[i]);
}

// ------------- W[K,Nc] -> WT[Npad,K] bf16, zero-pad rows >= Nc --------------
__global__ void wt_build_kernel(const float* __restrict__ W, bf16* __restrict__ WT,
                                int K, int Nc, int Npad) {
  int idx = blockIdx.x * blockDim.x + threadIdx.x;
  if (idx >= Npad * K) return;
  int n = idx / K, k = idx - n * K;
  WT[idx] = __float2bfloat16(n < Nc ? W[(size_t)k * Nc + n] : 0.f);
}

// ------------- el/er: per (node,head) dot(f[n,h,:], al[h,:]) ----------------
template <int H>
__global__ void el_er_kernel(const bf16* __restrict__ f, const float* __restrict__ al,
                             const float* __restrict__ ar, float* __restrict__ el,
                             float* __restrict__ er, int N, int D) {
  int gtid = blockIdx.x * blockDim.x + threadIdx.x;
  int wave = gtid >> 6, lane = gtid & 63;
  if (wave >= N * H) return;
  int h = wave % H;
  const short* frow = (const short*)f + (size_t)wave * D;
  float sl = 0.f, sr = 0.f;
  for (int d = lane; d < D; d += 64) {
    float v = bf2f(frow[d]);
    sl += v * al[h * D + d];
    sr += v * ar[h * D + d];
  }
#pragma unroll
  for (int off = 32; off > 0; off >>= 1) {
    sl += __shfl_down(sl, off);
    sr += __shfl_down(sr, off);
  }
  if (lane == 0) { el[wave] = sl; er[wave] = sr; }
}

// ------------- edge pass 1: leaky score + segment max (encoded atomicMax) ---
template <int H>
__global__ void edge_score_kernel(const int* __restrict__ src, const int* __restrict__ dst,
                                  const float* __restrict__ el, const float* __restrict__ er,
                                  float* __restrict__ sc, unsigned int* __restrict__ menc, int E) {
  int i = blockIdx.x * blockDim.x + threadIdx.x;
  if (i >= E * H) return;
  int e = i / H, h = i - e * H;
  int s = src[e], d = dst[e];
  float v = el[s * H + h] + er[d * H + h];
  v = v > 0.f ? v : SLOPE * v;
  sc[i] = v;
  unsigned int u = __float_as_uint(v);
  u = (u & 0x80000000u) ? ~u : (u | 0x80000000u);
  atomicMax(menc + d * H + h, u);
}

// ------------- edge pass 2: ex = exp(sc - m[dst]); segment sum --------------
template <int H>
__global__ void edge_exp_kernel(const int* __restrict__ dst, float* __restrict__ sc,
                                const unsigned int* __restrict__ menc,
                                float* __restrict__ ssum, int E) {
  int i = blockIdx.x * blockDim.x + threadIdx.x;
  if (i >= E * H) return;
  int e = i / H, h = i - e * H;
  int d = dst[e];
  unsigned int u = menc[d * H + h];
  float m = (u & 0x80000000u) ? __uint_as_float(u ^ 0x80000000u) : __uint_as_float(~u);
  float ex = __expf(sc[i] - m);
  sc[i] = ex;
  atomicAdd(ssum + d * H + h, ex);
}

// ------------- edge pass 3 (D=128): wave per (edge,head), grid-stride -------
template <int H>
__global__ void edge_aggr128_kernel(const int* __restrict__ src, const int* __restrict__ dst,
                                    const bf16* __restrict__ f, const float* __restrict__ ex,
                                    const float* __restrict__ ssum, float* __restrict__ out, int E) {
  int gw = (blockIdx.x * blockDim.x + threadIdx.x) >> 6;
  int lane = threadIdx.x & 63;
  int nw = (gridDim.x * blockDim.x) >> 6;
  const short* fs = (const short*)f;
  for (int i = gw; i < E * H; i += nw) {
    int e = i / H, h = i - e * H;
    int s = src[e], d = dst[e];
    float a = ex[i] / ssum[d * H + h];
    size_t fb = ((size_t)s * H + h) * 128;
    size_t ob = ((size_t)d * H + h) * 128;
    float v0 = bf2f(fs[fb + lane]) * a;
    float v1 = bf2f(fs[fb + 64 + lane]) * a;
    atomicAdd(out + ob + lane, v0);
    atomicAdd(out + ob + 64 + lane, v1);
  }
}

// ------------- edge pass 3 (D=40, H=1): wave per edge -----------------------
__global__ void edge_aggr40_kernel(const int* __restrict__ src, const int* __restrict__ dst,
                                   const bf16* __restrict__ f, const float* __restrict__ ex,
                                   const float* __restrict__ ssum, float* __restrict__ out, int E) {
  int gw = (blockIdx.x * blockDim.x + threadIdx.x) >> 6;
  int lane = threadIdx.x & 63;
  int nw = (gridDim.x * blockDim.x) >> 6;
  const short* fs = (const short*)f;
  for (int e = gw; e < E; e += nw) {
    int s = src[e], d = dst[e];
    float a = ex[e] / ssum[d];
    if (lane < F_OUT) {
      float v = bf2f(fs[(size_t)s * F_OUT + lane]) * a;
      atomicAdd(out + (size_t)d * F_OUT + lane, v);
    }
  }
}

// ------------- BN stats: per-channel sum / sumsq ----------------------------
__global__ void bn_stats_kernel(const float* __restrict__ h, float* __restrict__ sum,
                                float* __restrict__ sumsq, int N, int C) {
  int c = threadIdx.x;  // blockDim.x == C
  float s = 0.f, s2 = 0.f;
  for (int n = blockIdx.x; n < N; n += gridDim.x) {
    float v = h[(size_t)n * C + c];
    s += v; s2 += v * v;
  }
  atomicAdd(sum + c, s);
  atomicAdd(sumsq + c, s2);
}

// ------------- BN apply + ReLU -> bf16 (next layer's GEMM input) ------------
__global__ void bn_apply_kernel(const float* __restrict__ h, const float* __restrict__ sum,
                                const float* __restrict__ sumsq, const float* __restrict__ g,
                                const float* __restrict__ be, bf16* __restrict__ out,
                                int N, int C) {
  int i = blockIdx.x * blockDim.x + threadIdx.x;
  if (i >= N * C) return;
  int c = i % C;
  float inv_n = 1.f / (float)N;
  float mu = sum[c] * inv_n;
  float var = sumsq[c] * inv_n - mu * mu;
  float v = (h[i] - mu) * rsqrtf(var + BN_EPS) * g[c] + be[c];
  out[i] = __float2bfloat16(v > 0.f ? v : 0.f);
}

// ------------- final: add bias, fp32 output ---------------------------------
__global__ void final_kernel(const float* __restrict__ o, const float* __restrict__ b,
                             float* __restrict__ out, int N, int C) {
  int i = blockIdx.x * blockDim.x + threadIdx.x;
  if (i >= N * C) return;
  int c = i % C;
  out[i] = o[i] + b[c];
}

static inline int cdiv(int a, int b) { return (a + b - 1) / b; }

extern "C" void kernel_launch(void* const* d_in, const int* in_sizes, int n_in,
                              void* d_out, int out_size, void* d_ws, size_t ws_size,
                              hipStream_t stream) {
  const float* x   = (const float*)d_in[0];
  const int* src   = (const int*)d_in[1];
  const int* dst   = (const int*)d_in[2];
  const float* W0  = (const float*)d_in[3];
  const float* al0 = (const float*)d_in[4];
  const float* ar0 = (const float*)d_in[5];
  // b0/b1 are zeros and cancel under BN anyway
  const float* W1  = (const float*)d_in[7];
  const float* al1 = (const float*)d_in[8];
  const float* ar1 = (const float*)d_in[9];
  const float* W2  = (const float*)d_in[11];
  const float* al2 = (const float*)d_in[12];
  const float* ar2 = (const float*)d_in[13];
  const float* b2  = (const float*)d_in[14];
  const float* g0  = (const float*)d_in[15];
  const float* be0 = (const float*)d_in[16];
  const float* g1  = (const float*)d_in[17];
  const float* be1 = (const float*)d_in[18];
  float* out = (float*)d_out;

  const int N = N_NODES, E = N_EDGES, H = H_HEADS, D = D_HID;
  const int C = H * D;  // 384

  // ---- workspace carve ----
  char* p = (char*)d_ws;
  auto take = [&](size_t bytes) {
    char* r = p;
    p += (bytes + 255) & ~(size_t)255;
    return r;
  };
  bf16*  f_buf = (bf16*) take((size_t)N * C * sizeof(bf16));   // GEMM output (all layers)
  float* hbuf  = (float*)take((size_t)N * C * sizeof(float));  // fp32 aggregation buffer
  bf16*  abuf  = (bf16*) take((size_t)N * C * sizeof(bf16));   // bf16 GEMM A input (x cast / BN out)
  float* exb   = (float*)take((size_t)E * H * sizeof(float));  // edge scores / exp
  float* el    = (float*)take((size_t)N * H * sizeof(float));
  float* er    = (float*)take((size_t)N * H * sizeof(float));
  unsigned int* menc = (unsigned int*)take((size_t)N * H * sizeof(unsigned int));
  float* ssum  = (float*)take((size_t)N * H * sizeof(float));
  float* bnsum = (float*)take((size_t)C * sizeof(float));
  float* bnsq  = (float*)take((size_t)C * sizeof(float));
  float* out2  = (float*)take((size_t)N * F_OUT * sizeof(float));
  bf16*  WT0   = (bf16*) take((size_t)C * F_IN * sizeof(bf16));   // [384,128]
  bf16*  WT1   = (bf16*) take((size_t)C * C * sizeof(bf16));      // [384,384]
  bf16*  WT2   = (bf16*) take((size_t)64 * C * sizeof(bf16));     // [64,384] rows>=40 zero

  // ---- weight prep (small) ----
  wt_build_kernel<<<cdiv(C * F_IN, 256), 256, 0, stream>>>(W0, WT0, F_IN, C, C);
  wt_build_kernel<<<cdiv(C * C, 256), 256, 0, stream>>>(W1, WT1, C, C, C);
  wt_build_kernel<<<cdiv(64 * C, 256), 256, 0, stream>>>(W2, WT2, C, F_OUT, 64);
  cast_bf16_kernel<<<1024, 256, 0, stream>>>(x, abuf, N * F_IN);

  // ================= layer 0: abuf[N,128] -> hbuf[N,384] =================
  gemm_mfma<<<dim3(C / 64, cdiv(N, 64)), 256, 0, stream>>>((const short*)abuf, (const short*)WT0,
                                                           f_buf, N, F_IN, C);
  hipMemsetAsync(hbuf, 0, (size_t)N * C * sizeof(float), stream);
  hipMemsetAsync(menc, 0, (size_t)N * H * sizeof(unsigned int), stream);
  hipMemsetAsync(ssum, 0, (size_t)N * H * sizeof(float), stream);
  hipMemsetAsync(bnsum, 0, C * sizeof(float), stream);
  hipMemsetAsync(bnsq,  0, C * sizeof(float), stream);
  el_er_kernel<H_HEADS><<<cdiv(N * H * 64, 256), 256, 0, stream>>>(f_buf, al0, ar0, el, er, N, D);
  edge_score_kernel<H_HEADS><<<cdiv(E * H, 256), 256, 0, stream>>>(src, dst, el, er, exb, menc, E);
  edge_exp_kernel<H_HEADS><<<cdiv(E * H, 256), 256, 0, stream>>>(dst, exb, menc, ssum, E);
  edge_aggr128_kernel<H_HEADS><<<2048, 256, 0, stream>>>(src, dst, f_buf, exb, ssum, hbuf, E);
  bn_stats_kernel<<<256, C, 0, stream>>>(hbuf, bnsum, bnsq, N, C);
  bn_apply_kernel<<<cdiv(N * C, 256), 256, 0, stream>>>(hbuf, bnsum, bnsq, g0, be0, abuf, N, C);

  // ================= layer 1: abuf[N,384] -> hbuf[N,384] =================
  gemm_mfma<<<dim3(C / 64, cdiv(N, 64)), 256, 0, stream>>>((const short*)abuf, (const short*)WT1,
                                                           f_buf, N, C, C);
  hipMemsetAsync(hbuf, 0, (size_t)N * C * sizeof(float), stream);
  hipMemsetAsync(menc, 0, (size_t)N * H * sizeof(unsigned int), stream);
  hipMemsetAsync(ssum, 0, (size_t)N * H * sizeof(float), stream);
  hipMemsetAsync(bnsum, 0, C * sizeof(float), stream);
  hipMemsetAsync(bnsq,  0, C * sizeof(float), stream);
  el_er_kernel<H_HEADS><<<cdiv(N * H * 64, 256), 256, 0, stream>>>(f_buf, al1, ar1, el, er, N, D);
  edge_score_kernel<H_HEADS><<<cdiv(E * H, 256), 256, 0, stream>>>(src, dst, el, er, exb, menc, E);
  edge_exp_kernel<H_HEADS><<<cdiv(E * H, 256), 256, 0, stream>>>(dst, exb, menc, ssum, E);
  edge_aggr128_kernel<H_HEADS><<<2048, 256, 0, stream>>>(src, dst, f_buf, exb, ssum, hbuf, E);
  bn_stats_kernel<<<256, C, 0, stream>>>(hbuf, bnsum, bnsq, N, C);
  bn_apply_kernel<<<cdiv(N * C, 256), 256, 0, stream>>>(hbuf, bnsum, bnsq, g1, be1, abuf, N, C);

  // ================= layer 2: abuf[N,384] -> out[N,40], 1 head ============
  gemm_mfma<<<dim3(1, cdiv(N, 64)), 256, 0, stream>>>((const short*)abuf, (const short*)WT2,
                                                      f_buf, N, C, F_OUT);
  hipMemsetAsync(out2, 0, (size_t)N * F_OUT * sizeof(float), stream);
  hipMemsetAsync(menc, 0, (size_t)N * sizeof(unsigned int), stream);
  hipMemsetAsync(ssum, 0, (size_t)N * sizeof(float), stream);
  el_er_kernel<1><<<cdiv(N * 64, 256), 256, 0, stream>>>(f_buf, al2, ar2, el, er, N, F_OUT);
  edge_score_kernel<1><<<cdiv(E, 256), 256, 0, stream>>>(src, dst, el, er, exb, menc, E);
  edge_exp_kernel<1><<<cdiv(E, 256), 256, 0, stream>>>(dst, exb, menc, ssum, E);
  edge_aggr40_kernel<<<2048, 256, 0, stream>>>(src, dst, f_buf, exb, ssum, out2, E);
  final_kernel<<<cdiv(N * F_OUT, 256), 256, 0, stream>>>(out2, b2, out, N, F_OUT);
}

// Round 5
// 1188.347 us; speedup vs baseline: 3.4694x; 2.3604x over previous
//
#include <hip/hip_runtime.h>
#include <hip/hip_bf16.h>

typedef __hip_bfloat16 bf16;
typedef __attribute__((ext_vector_type(8))) short short8;
typedef __attribute__((ext_vector_type(4))) float f32x4;

static constexpr int N_NODES  = 50000;
static constexpr int N_EDGES  = 800000;
static constexpr int F_IN     = 128;
static constexpr int D_HID    = 128;
static constexpr int H_HEADS  = 3;
static constexpr int F_OUT    = 40;
static constexpr float BN_EPS = 1e-5f;
static constexpr float SLOPE  = 0.2f;

__device__ __forceinline__ float bf2f(unsigned short s) {
  return __uint_as_float(((unsigned int)s) << 16);
}

// ---------------- MFMA GEMM: C[M,Nc] = A[M,K] @ WT[Nc,K]^T, bf16 in/out -----
__global__ __launch_bounds__(256) void gemm_mfma(const short* __restrict__ A,
                                                 const short* __restrict__ WT,
                                                 bf16* __restrict__ C,
                                                 int M, int K, int Nc) {
  constexpr int BM = 64, BN = 64, BK = 64, LDP = BK + 8;
  __shared__ short As[BM * LDP];
  __shared__ short Bs[BN * LDP];
  int tid = threadIdx.x;
  int wave = tid >> 6, lane = tid & 63;
  int bm = blockIdx.y, bn = blockIdx.x;
  int lrow = tid >> 3;
  int kcol = (tid & 7) * 8;

  f32x4 acc[4];
#pragma unroll
  for (int i = 0; i < 4; ++i) acc[i] = (f32x4){0.f, 0.f, 0.f, 0.f};

  int m15 = lane & 15;
  int ksub = (lane >> 4) * 8;

  for (int k0 = 0; k0 < K; k0 += BK) {
#pragma unroll
    for (int c = 0; c < 2; ++c) {
      int r = lrow + c * 32;
      int gr = bm * BM + r; if (gr >= M) gr = M - 1;
      *(short8*)&As[r * LDP + kcol] = *(const short8*)&A[(size_t)gr * K + k0 + kcol];
      int gn = bn * BN + r;
      *(short8*)&Bs[r * LDP + kcol] = *(const short8*)&WT[(size_t)gn * K + k0 + kcol];
    }
    __syncthreads();
#pragma unroll
    for (int ks = 0; ks < BK; ks += 32) {
      short8 a = *(const short8*)&As[(wave * 16 + m15) * LDP + ks + ksub];
#pragma unroll
      for (int nb = 0; nb < 4; ++nb) {
        short8 b = *(const short8*)&Bs[(nb * 16 + m15) * LDP + ks + ksub];
        acc[nb] = __builtin_amdgcn_mfma_f32_16x16x32_bf16(a, b, acc[nb], 0, 0, 0);
      }
    }
    __syncthreads();
  }
#pragma unroll
  for (int nb = 0; nb < 4; ++nb) {
    int col = bn * BN + nb * 16 + m15;
#pragma unroll
    for (int r = 0; r < 4; ++r) {
      int row = bm * BM + wave * 16 + (lane >> 4) * 4 + r;
      if (row < M && col < Nc)
        C[(size_t)row * Nc + col] = __float2bfloat16(acc[nb][r]);
    }
  }
}

// ------------- cast fp32 -> bf16 --------------------------------------------
__global__ void cast_bf16_kernel(const float* __restrict__ in, bf16* __restrict__ out, int n) {
  for (int i = blockIdx.x * blockDim.x + threadIdx.x; i < n; i += gridDim.x * blockDim.x)
    out[i] = __float2bfloat16(in[i]);
}

// ------------- W[K,Nc] -> WT[Npad,K] bf16, zero-pad rows >= Nc --------------
__global__ void wt_build_kernel(const float* __restrict__ W, bf16* __restrict__ WT,
                                int K, int Nc, int Npad) {
  int idx = blockIdx.x * blockDim.x + threadIdx.x;
  if (idx >= Npad * K) return;
  int n = idx / K, k = idx - n * K;
  WT[idx] = __float2bfloat16(n < Nc ? W[(size_t)k * Nc + n] : 0.f);
}

// ------------- CSR build ----------------------------------------------------
__global__ void hist_kernel(const int* __restrict__ dst, int* __restrict__ cnt, int E) {
  int i = blockIdx.x * blockDim.x + threadIdx.x;
  if (i < E) atomicAdd(cnt + dst[i], 1);
}

__global__ void scan_kernel(const int* __restrict__ cnt, int* __restrict__ row_ptr,
                            int N, int E) {
  __shared__ int part[256];
  int t = threadIdx.x;
  int chunk = (N + 255) / 256;
  int b = t * chunk, e = min(b + chunk, N);
  int s = 0;
  for (int i = b; i < e; ++i) s += cnt[i];
  part[t] = s;
  __syncthreads();
  for (int off = 1; off < 256; off <<= 1) {
    int v = (t >= off) ? part[t - off] : 0;
    __syncthreads();
    part[t] += v;
    __syncthreads();
  }
  int run = (t == 0) ? 0 : part[t - 1];
  for (int i = b; i < e; ++i) { row_ptr[i] = run; run += cnt[i]; }
  if (t == 255) row_ptr[N] = E;
}

__global__ void scatter_kernel(const int* __restrict__ src, const int* __restrict__ dst,
                               const int* __restrict__ row_ptr, int* __restrict__ fill,
                               int* __restrict__ csr_src, int E) {
  int i = blockIdx.x * blockDim.x + threadIdx.x;
  if (i < E) {
    int d = dst[i];
    int pos = row_ptr[d] + atomicAdd(fill + d, 1);
    csr_src[pos] = src[i];
  }
}

// ------------- el/er: per (node,head) dot(f[n,h,:], a[h,:]) -----------------
template <int H>
__global__ void el_er_kernel(const bf16* __restrict__ f, const float* __restrict__ al,
                             const float* __restrict__ ar, float* __restrict__ el,
                             float* __restrict__ er, int N, int D) {
  int gtid = blockIdx.x * blockDim.x + threadIdx.x;
  int wave = gtid >> 6, lane = gtid & 63;
  if (wave >= N * H) return;
  int h = wave % H;
  const unsigned short* frow = (const unsigned short*)f + (size_t)wave * D;
  float sl = 0.f, sr = 0.f;
  for (int d = lane; d < D; d += 64) {
    float v = bf2f(frow[d]);
    sl += v * al[h * D + d];
    sr += v * ar[h * D + d];
  }
#pragma unroll
  for (int off = 32; off > 0; off >>= 1) {
    sl += __shfl_down(sl, off);
    sr += __shfl_down(sr, off);
  }
  if (lane == 0) { el[wave] = sl; er[wave] = sr; }
}

// ------------- fused GAT: online-softmax + gather aggregation ---------------
// one wave per (dst, head); f rows gathered as uint (2x bf16)/lane; single write.
template <int H, int D>
__global__ __launch_bounds__(256) void gat_fused_kernel(
    const int* __restrict__ row_ptr, const int* __restrict__ csr_src,
    const bf16* __restrict__ f, const float* __restrict__ el,
    const float* __restrict__ er, const float* __restrict__ bias,
    float* __restrict__ out, int N) {
  int gw = (blockIdx.x * 256 + threadIdx.x) >> 6;
  int lane = threadIdx.x & 63;
  if (gw >= N * H) return;
  int d = gw / H, h = gw - d * H;
  int beg = row_ptr[d], end = row_ptr[d + 1];
  float er_d = er[d * H + h];
  constexpr int DW = D / 2;
  const unsigned int* fu = (const unsigned int*)f;
  float m = -1e30f, ssum = 0.f, a0 = 0.f, a1 = 0.f;
  for (int k = beg; k < end; ++k) {
    int s = csr_src[k];
    float sc = el[s * H + h] + er_d;
    sc = sc > 0.f ? sc : SLOPE * sc;
    float mn = fmaxf(m, sc);
    float f1 = __expf(m - mn);
    float w  = __expf(sc - mn);
    ssum = ssum * f1 + w;
    m = mn;
    if (lane < DW) {
      unsigned int u = fu[((size_t)s * H + h) * DW + lane];
      float v0 = bf2f((unsigned short)(u & 0xffffu));
      float v1 = bf2f((unsigned short)(u >> 16));
      a0 = a0 * f1 + w * v0;
      a1 = a1 * f1 + w * v1;
    }
  }
  float inv = 1.f / ssum;
  if (lane < DW) {
    float o0 = a0 * inv, o1 = a1 * inv;
    if (bias) { o0 += bias[2 * lane]; o1 += bias[2 * lane + 1]; }
    *(float2*)&out[((size_t)d * H + h) * D + 2 * lane] = make_float2(o0, o1);
  }
}

// ------------- BN stats -----------------------------------------------------
__global__ void bn_stats_kernel(const float* __restrict__ h, float* __restrict__ sum,
                                float* __restrict__ sumsq, int N, int C) {
  int c = threadIdx.x;
  float s = 0.f, s2 = 0.f;
  for (int n = blockIdx.x; n < N; n += gridDim.x) {
    float v = h[(size_t)n * C + c];
    s += v; s2 += v * v;
  }
  atomicAdd(sum + c, s);
  atomicAdd(sumsq + c, s2);
}

// ------------- BN apply + ReLU -> bf16 --------------------------------------
__global__ void bn_apply_kernel(const float* __restrict__ h, const float* __restrict__ sum,
                                const float* __restrict__ sumsq, const float* __restrict__ g,
                                const float* __restrict__ be, bf16* __restrict__ out,
                                int N, int C) {
  int i = blockIdx.x * blockDim.x + threadIdx.x;
  if (i >= N * C) return;
  int c = i % C;
  float inv_n = 1.f / (float)N;
  float mu = sum[c] * inv_n;
  float var = sumsq[c] * inv_n - mu * mu;
  float v = (h[i] - mu) * rsqrtf(var + BN_EPS) * g[c] + be[c];
  out[i] = __float2bfloat16(v > 0.f ? v : 0.f);
}

static inline int cdiv(int a, int b) { return (a + b - 1) / b; }

extern "C" void kernel_launch(void* const* d_in, const int* in_sizes, int n_in,
                              void* d_out, int out_size, void* d_ws, size_t ws_size,
                              hipStream_t stream) {
  const float* x   = (const float*)d_in[0];
  const int* src   = (const int*)d_in[1];
  const int* dst   = (const int*)d_in[2];
  const float* W0  = (const float*)d_in[3];
  const float* al0 = (const float*)d_in[4];
  const float* ar0 = (const float*)d_in[5];
  const float* W1  = (const float*)d_in[7];
  const float* al1 = (const float*)d_in[8];
  const float* ar1 = (const float*)d_in[9];
  const float* W2  = (const float*)d_in[11];
  const float* al2 = (const float*)d_in[12];
  const float* ar2 = (const float*)d_in[13];
  const float* b2  = (const float*)d_in[14];
  const float* g0  = (const float*)d_in[15];
  const float* be0 = (const float*)d_in[16];
  const float* g1  = (const float*)d_in[17];
  const float* be1 = (const float*)d_in[18];
  float* out = (float*)d_out;

  const int N = N_NODES, E = N_EDGES, H = H_HEADS, D = D_HID;
  const int C = H * D;  // 384

  // ---- workspace carve ----
  char* p = (char*)d_ws;
  auto take = [&](size_t bytes) {
    char* r = p;
    p += (bytes + 255) & ~(size_t)255;
    return r;
  };
  bf16*  f_buf = (bf16*) take((size_t)N * C * sizeof(bf16));
  float* hbuf  = (float*)take((size_t)N * C * sizeof(float));
  bf16*  abuf  = (bf16*) take((size_t)N * C * sizeof(bf16));
  float* el    = (float*)take((size_t)N * H * sizeof(float));
  float* er    = (float*)take((size_t)N * H * sizeof(float));
  float* bnsum = (float*)take((size_t)C * sizeof(float));
  float* bnsq  = (float*)take((size_t)C * sizeof(float));
  bf16*  WT0   = (bf16*) take((size_t)C * F_IN * sizeof(bf16));
  bf16*  WT1   = (bf16*) take((size_t)C * C * sizeof(bf16));
  bf16*  WT2   = (bf16*) take((size_t)64 * C * sizeof(bf16));
  int*   cnt     = (int*)take((size_t)N * sizeof(int));
  int*   row_ptr = (int*)take((size_t)(N + 1) * sizeof(int));
  int*   csr_src = (int*)take((size_t)E * sizeof(int));

  // ---- CSR build (by dst) ----
  hipMemsetAsync(cnt, 0, N * sizeof(int), stream);
  hist_kernel<<<cdiv(E, 256), 256, 0, stream>>>(dst, cnt, E);
  scan_kernel<<<1, 256, 0, stream>>>(cnt, row_ptr, N, E);
  hipMemsetAsync(cnt, 0, N * sizeof(int), stream);
  scatter_kernel<<<cdiv(E, 256), 256, 0, stream>>>(src, dst, row_ptr, cnt, csr_src, E);

  // ---- weight prep ----
  wt_build_kernel<<<cdiv(C * F_IN, 256), 256, 0, stream>>>(W0, WT0, F_IN, C, C);
  wt_build_kernel<<<cdiv(C * C, 256), 256, 0, stream>>>(W1, WT1, C, C, C);
  wt_build_kernel<<<cdiv(64 * C, 256), 256, 0, stream>>>(W2, WT2, C, F_OUT, 64);
  cast_bf16_kernel<<<1024, 256, 0, stream>>>(x, abuf, N * F_IN);

  // ================= layer 0 =================
  gemm_mfma<<<dim3(C / 64, cdiv(N, 64)), 256, 0, stream>>>((const short*)abuf, (const short*)WT0,
                                                           f_buf, N, F_IN, C);
  hipMemsetAsync(bnsum, 0, C * sizeof(float), stream);
  hipMemsetAsync(bnsq,  0, C * sizeof(float), stream);
  el_er_kernel<H_HEADS><<<cdiv(N * H * 64, 256), 256, 0, stream>>>(f_buf, al0, ar0, el, er, N, D);
  gat_fused_kernel<H_HEADS, D_HID><<<cdiv(N * H * 64, 256), 256, 0, stream>>>(
      row_ptr, csr_src, f_buf, el, er, nullptr, hbuf, N);
  bn_stats_kernel<<<256, C, 0, stream>>>(hbuf, bnsum, bnsq, N, C);
  bn_apply_kernel<<<cdiv(N * C, 256), 256, 0, stream>>>(hbuf, bnsum, bnsq, g0, be0, abuf, N, C);

  // ================= layer 1 =================
  gemm_mfma<<<dim3(C / 64, cdiv(N, 64)), 256, 0, stream>>>((const short*)abuf, (const short*)WT1,
                                                           f_buf, N, C, C);
  hipMemsetAsync(bnsum, 0, C * sizeof(float), stream);
  hipMemsetAsync(bnsq,  0, C * sizeof(float), stream);
  el_er_kernel<H_HEADS><<<cdiv(N * H * 64, 256), 256, 0, stream>>>(f_buf, al1, ar1, el, er, N, D);
  gat_fused_kernel<H_HEADS, D_HID><<<cdiv(N * H * 64, 256), 256, 0, stream>>>(
      row_ptr, csr_src, f_buf, el, er, nullptr, hbuf, N);
  bn_stats_kernel<<<256, C, 0, stream>>>(hbuf, bnsum, bnsq, N, C);
  bn_apply_kernel<<<cdiv(N * C, 256), 256, 0, stream>>>(hbuf, bnsum, bnsq, g1, be1, abuf, N, C);

  // ================= layer 2 (H=1, D=40, bias fused, direct to out) =========
  gemm_mfma<<<dim3(1, cdiv(N, 64)), 256, 0, stream>>>((const short*)abuf, (const short*)WT2,
                                                      f_buf, N, C, F_OUT);
  el_er_kernel<1><<<cdiv(N * 64, 256), 256, 0, stream>>>(f_buf, al2, ar2, el, er, N, F_OUT);
  gat_fused_kernel<1, F_OUT><<<cdiv(N * 64, 256), 256, 0, stream>>>(
      row_ptr, csr_src, f_buf, el, er, b2, out, N);
}

// Round 6
// 1004.081 us; speedup vs baseline: 4.1060x; 1.1835x over previous
//
#include <hip/hip_runtime.h>
#include <hip/hip_bf16.h>

typedef __hip_bfloat16 bf16;
typedef __attribute__((ext_vector_type(8))) short short8;
typedef __attribute__((ext_vector_type(4))) float f32x4;

static constexpr int N_NODES  = 50000;
static constexpr int N_EDGES  = 800000;
static constexpr int F_IN     = 128;
static constexpr int D_HID    = 128;
static constexpr int H_HEADS  = 3;
static constexpr int F_OUT    = 40;
static constexpr float BN_EPS = 1e-5f;
static constexpr float SLOPE  = 0.2f;

__device__ __forceinline__ float bf2f(unsigned int s) {
  return __uint_as_float(s << 16);
}

// ---------------- MFMA GEMM: C[M,Nc] = A[M,K] @ WT[Nc,K]^T, bf16 in/out -----
__global__ __launch_bounds__(256) void gemm_mfma(const short* __restrict__ A,
                                                 const short* __restrict__ WT,
                                                 bf16* __restrict__ C,
                                                 int M, int K, int Nc) {
  constexpr int BM = 64, BN = 64, BK = 64, LDP = BK + 8;
  __shared__ short As[BM * LDP];
  __shared__ short Bs[BN * LDP];
  int tid = threadIdx.x;
  int wave = tid >> 6, lane = tid & 63;
  int bm = blockIdx.y, bn = blockIdx.x;
  int lrow = tid >> 3;
  int kcol = (tid & 7) * 8;

  f32x4 acc[4];
#pragma unroll
  for (int i = 0; i < 4; ++i) acc[i] = (f32x4){0.f, 0.f, 0.f, 0.f};

  int m15 = lane & 15;
  int ksub = (lane >> 4) * 8;

  for (int k0 = 0; k0 < K; k0 += BK) {
#pragma unroll
    for (int c = 0; c < 2; ++c) {
      int r = lrow + c * 32;
      int gr = bm * BM + r; if (gr >= M) gr = M - 1;
      *(short8*)&As[r * LDP + kcol] = *(const short8*)&A[(size_t)gr * K + k0 + kcol];
      int gn = bn * BN + r;
      *(short8*)&Bs[r * LDP + kcol] = *(const short8*)&WT[(size_t)gn * K + k0 + kcol];
    }
    __syncthreads();
#pragma unroll
    for (int ks = 0; ks < BK; ks += 32) {
      short8 a = *(const short8*)&As[(wave * 16 + m15) * LDP + ks + ksub];
#pragma unroll
      for (int nb = 0; nb < 4; ++nb) {
        short8 b = *(const short8*)&Bs[(nb * 16 + m15) * LDP + ks + ksub];
        acc[nb] = __builtin_amdgcn_mfma_f32_16x16x32_bf16(a, b, acc[nb], 0, 0, 0);
      }
    }
    __syncthreads();
  }
#pragma unroll
  for (int nb = 0; nb < 4; ++nb) {
    int col = bn * BN + nb * 16 + m15;
#pragma unroll
    for (int r = 0; r < 4; ++r) {
      int row = bm * BM + wave * 16 + (lane >> 4) * 4 + r;
      if (row < M && col < Nc)
        C[(size_t)row * Nc + col] = __float2bfloat16(acc[nb][r]);
    }
  }
}

// ------------- cast fp32 -> bf16 --------------------------------------------
__global__ void cast_bf16_kernel(const float* __restrict__ in, bf16* __restrict__ out, int n) {
  for (int i = blockIdx.x * blockDim.x + threadIdx.x; i < n; i += gridDim.x * blockDim.x)
    out[i] = __float2bfloat16(in[i]);
}

// ------------- W[K,Nc] -> WT[Npad,K] bf16, zero-pad rows >= Nc --------------
__global__ void wt_build_kernel(const float* __restrict__ W, bf16* __restrict__ WT,
                                int K, int Nc, int Npad) {
  int idx = blockIdx.x * blockDim.x + threadIdx.x;
  if (idx >= Npad * K) return;
  int n = idx / K, k = idx - n * K;
  WT[idx] = __float2bfloat16(n < Nc ? W[(size_t)k * Nc + n] : 0.f);
}

// ------------- CSR build ----------------------------------------------------
__global__ void hist_kernel(const int* __restrict__ dst, int* __restrict__ cnt, int E) {
  int i = blockIdx.x * blockDim.x + threadIdx.x;
  if (i < E) atomicAdd(cnt + dst[i], 1);
}

__global__ void scan_kernel(const int* __restrict__ cnt, int* __restrict__ row_ptr,
                            int N, int E) {
  __shared__ int part[256];
  int t = threadIdx.x;
  int chunk = (N + 255) / 256;
  int b = t * chunk, e = min(b + chunk, N);
  int s = 0;
  for (int i = b; i < e; ++i) s += cnt[i];
  part[t] = s;
  __syncthreads();
  for (int off = 1; off < 256; off <<= 1) {
    int v = (t >= off) ? part[t - off] : 0;
    __syncthreads();
    part[t] += v;
    __syncthreads();
  }
  int run = (t == 0) ? 0 : part[t - 1];
  for (int i = b; i < e; ++i) { row_ptr[i] = run; run += cnt[i]; }
  if (t == 255) row_ptr[N] = E;
}

__global__ void scatter_kernel(const int* __restrict__ src, const int* __restrict__ dst,
                               const int* __restrict__ row_ptr, int* __restrict__ fill,
                               int* __restrict__ csr_src, int* __restrict__ csr_dst, int E) {
  int i = blockIdx.x * blockDim.x + threadIdx.x;
  if (i < E) {
    int d = dst[i];
    int pos = row_ptr[d] + atomicAdd(fill + d, 1);
    csr_src[pos] = src[i];
    csr_dst[pos] = d;
  }
}

// ------------- el/er: per (node,head) dot(f[n,h,:], a[h,:]) -----------------
template <int H>
__global__ void el_er_kernel(const bf16* __restrict__ f, const float* __restrict__ al,
                             const float* __restrict__ ar, float* __restrict__ el,
                             float* __restrict__ er, int N, int D) {
  int gtid = blockIdx.x * blockDim.x + threadIdx.x;
  int wave = gtid >> 6, lane = gtid & 63;
  if (wave >= N * H) return;
  int h = wave % H;
  const unsigned short* frow = (const unsigned short*)f + (size_t)wave * D;
  float sl = 0.f, sr = 0.f;
  for (int d = lane; d < D; d += 64) {
    float v = bf2f((unsigned int)frow[d]);
    sl += v * al[h * D + d];
    sr += v * ar[h * D + d];
  }
#pragma unroll
  for (int off = 32; off > 0; off >>= 1) {
    sl += __shfl_down(sl, off);
    sr += __shfl_down(sr, off);
  }
  if (lane == 0) { el[wave] = sl; er[wave] = sr; }
}

// ------------- pass A: per (dst,head) online max + sum of exp ---------------
template <int H>
__global__ void score_stats_kernel(const int* __restrict__ row_ptr,
                                   const int* __restrict__ csr_src,
                                   const float* __restrict__ el,
                                   const float* __restrict__ er,
                                   float2* __restrict__ msum, int N) {
  int i = blockIdx.x * blockDim.x + threadIdx.x;
  if (i >= N * H) return;
  int d = i / H, h = i - d * H;
  int beg = row_ptr[d], end = row_ptr[d + 1];
  float erd = er[i];
  float m = -1e30f, s = 0.f;
  for (int k = beg; k < end; ++k) {
    int sn = csr_src[k];
    float sc = el[sn * H + h] + erd;
    sc = sc > 0.f ? sc : SLOPE * sc;
    float mn = fmaxf(m, sc);
    s = s * __expf(m - mn) + __expf(sc - mn);
    m = mn;
  }
  msum[i] = make_float2(m, 1.f / s);
}

// ------------- pass B: per CSR slot, normalized weight for all heads --------
template <int H>
__global__ void edge_w_kernel(const int* __restrict__ csr_src,
                              const int* __restrict__ csr_dst,
                              const float* __restrict__ el,
                              const float* __restrict__ er,
                              const float2* __restrict__ msum,
                              float* __restrict__ exw, int E) {
  int k = blockIdx.x * blockDim.x + threadIdx.x;
  if (k >= E) return;
  int s = csr_src[k], d = csr_dst[k];
#pragma unroll
  for (int h = 0; h < H; ++h) {
    float sc = el[s * H + h] + er[d * H + h];
    sc = sc > 0.f ? sc : SLOPE * sc;
    float2 t = msum[d * H + h];
    exw[k * H + h] = __expf(sc - t.x) * t.y;
  }
}

// ------------- pass C: weighted gather aggregation (no exp, unroll x2) ------
// wave per (dst,head); lane covers 2 channels via one uint (2x bf16).
template <int H, int DW>  // DW = D/2 words per row
__global__ __launch_bounds__(256) void aggr_kernel(
    const int* __restrict__ row_ptr, const int* __restrict__ csr_src,
    const float* __restrict__ exw, const bf16* __restrict__ f,
    const float* __restrict__ bias, float* __restrict__ out, int N) {
  int gw = (blockIdx.x * 256 + threadIdx.x) >> 6;
  int lane = threadIdx.x & 63;
  if (gw >= N * H) return;
  int d = gw / H, h = gw - d * H;
  int beg = row_ptr[d], end = row_ptr[d + 1];
  const unsigned int* fu = (const unsigned int*)f;
  if (lane < DW) {
    float a0 = 0.f, a1 = 0.f, b0 = 0.f, b1 = 0.f;
    int k = beg;
    for (; k + 1 < end; k += 2) {
      int s0 = csr_src[k], s1 = csr_src[k + 1];
      float w0 = exw[k * H + h], w1 = exw[(k + 1) * H + h];
      unsigned int u0 = fu[((size_t)s0 * H + h) * DW + lane];
      unsigned int u1 = fu[((size_t)s1 * H + h) * DW + lane];
      a0 += w0 * bf2f(u0 & 0xffffu);
      a1 += w0 * bf2f(u0 >> 16);
      b0 += w1 * bf2f(u1 & 0xffffu);
      b1 += w1 * bf2f(u1 >> 16);
    }
    if (k < end) {
      int s0 = csr_src[k];
      float w0 = exw[k * H + h];
      unsigned int u0 = fu[((size_t)s0 * H + h) * DW + lane];
      a0 += w0 * bf2f(u0 & 0xffffu);
      a1 += w0 * bf2f(u0 >> 16);
    }
    a0 += b0; a1 += b1;
    if (bias) { a0 += bias[2 * lane]; a1 += bias[2 * lane + 1]; }
    *(float2*)&out[((size_t)d * H + h) * (2 * DW) + 2 * lane] = make_float2(a0, a1);
  }
}

// ------------- BN stats -----------------------------------------------------
__global__ void bn_stats_kernel(const float* __restrict__ h, float* __restrict__ sum,
                                float* __restrict__ sumsq, int N, int C) {
  int c = threadIdx.x;
  float s = 0.f, s2 = 0.f;
  for (int n = blockIdx.x; n < N; n += gridDim.x) {
    float v = h[(size_t)n * C + c];
    s += v; s2 += v * v;
  }
  atomicAdd(sum + c, s);
  atomicAdd(sumsq + c, s2);
}

// ------------- BN apply + ReLU -> bf16 --------------------------------------
__global__ void bn_apply_kernel(const float* __restrict__ h, const float* __restrict__ sum,
                                const float* __restrict__ sumsq, const float* __restrict__ g,
                                const float* __restrict__ be, bf16* __restrict__ out,
                                int N, int C) {
  int i = blockIdx.x * blockDim.x + threadIdx.x;
  if (i >= N * C) return;
  int c = i % C;
  float inv_n = 1.f / (float)N;
  float mu = sum[c] * inv_n;
  float var = sumsq[c] * inv_n - mu * mu;
  float v = (h[i] - mu) * rsqrtf(var + BN_EPS) * g[c] + be[c];
  out[i] = __float2bfloat16(v > 0.f ? v : 0.f);
}

static inline int cdiv(int a, int b) { return (a + b - 1) / b; }

extern "C" void kernel_launch(void* const* d_in, const int* in_sizes, int n_in,
                              void* d_out, int out_size, void* d_ws, size_t ws_size,
                              hipStream_t stream) {
  const float* x   = (const float*)d_in[0];
  const int* src   = (const int*)d_in[1];
  const int* dst   = (const int*)d_in[2];
  const float* W0  = (const float*)d_in[3];
  const float* al0 = (const float*)d_in[4];
  const float* ar0 = (const float*)d_in[5];
  const float* W1  = (const float*)d_in[7];
  const float* al1 = (const float*)d_in[8];
  const float* ar1 = (const float*)d_in[9];
  const float* W2  = (const float*)d_in[11];
  const float* al2 = (const float*)d_in[12];
  const float* ar2 = (const float*)d_in[13];
  const float* b2  = (const float*)d_in[14];
  const float* g0  = (const float*)d_in[15];
  const float* be0 = (const float*)d_in[16];
  const float* g1  = (const float*)d_in[17];
  const float* be1 = (const float*)d_in[18];
  float* out = (float*)d_out;

  const int N = N_NODES, E = N_EDGES, H = H_HEADS, D = D_HID;
  const int C = H * D;  // 384

  // ---- workspace carve ----
  char* p = (char*)d_ws;
  auto take = [&](size_t bytes) {
    char* r = p;
    p += (bytes + 255) & ~(size_t)255;
    return r;
  };
  bf16*   f_buf   = (bf16*) take((size_t)N * C * sizeof(bf16));
  float*  hbuf    = (float*)take((size_t)N * C * sizeof(float));
  bf16*   abuf    = (bf16*) take((size_t)N * C * sizeof(bf16));
  float*  el      = (float*)take((size_t)N * H * sizeof(float));
  float*  er      = (float*)take((size_t)N * H * sizeof(float));
  float2* msum    = (float2*)take((size_t)N * H * sizeof(float2));
  float*  exw     = (float*)take((size_t)E * H * sizeof(float));
  float*  bnsum   = (float*)take((size_t)C * sizeof(float));
  float*  bnsq    = (float*)take((size_t)C * sizeof(float));
  bf16*   WT0     = (bf16*) take((size_t)C * F_IN * sizeof(bf16));
  bf16*   WT1     = (bf16*) take((size_t)C * C * sizeof(bf16));
  bf16*   WT2     = (bf16*) take((size_t)64 * C * sizeof(bf16));
  int*    cnt     = (int*)take((size_t)N * sizeof(int));
  int*    row_ptr = (int*)take((size_t)(N + 1) * sizeof(int));
  int*    csr_src = (int*)take((size_t)E * sizeof(int));
  int*    csr_dst = (int*)take((size_t)E * sizeof(int));

  // ---- CSR build (by dst) ----
  hipMemsetAsync(cnt, 0, N * sizeof(int), stream);
  hist_kernel<<<cdiv(E, 256), 256, 0, stream>>>(dst, cnt, E);
  scan_kernel<<<1, 256, 0, stream>>>(cnt, row_ptr, N, E);
  hipMemsetAsync(cnt, 0, N * sizeof(int), stream);
  scatter_kernel<<<cdiv(E, 256), 256, 0, stream>>>(src, dst, row_ptr, cnt, csr_src, csr_dst, E);

  // ---- weight prep ----
  wt_build_kernel<<<cdiv(C * F_IN, 256), 256, 0, stream>>>(W0, WT0, F_IN, C, C);
  wt_build_kernel<<<cdiv(C * C, 256), 256, 0, stream>>>(W1, WT1, C, C, C);
  wt_build_kernel<<<cdiv(64 * C, 256), 256, 0, stream>>>(W2, WT2, C, F_OUT, 64);
  cast_bf16_kernel<<<1024, 256, 0, stream>>>(x, abuf, N * F_IN);

  // ================= layer 0 =================
  gemm_mfma<<<dim3(C / 64, cdiv(N, 64)), 256, 0, stream>>>((const short*)abuf, (const short*)WT0,
                                                           f_buf, N, F_IN, C);
  hipMemsetAsync(bnsum, 0, C * sizeof(float), stream);
  hipMemsetAsync(bnsq,  0, C * sizeof(float), stream);
  el_er_kernel<H_HEADS><<<cdiv(N * H * 64, 256), 256, 0, stream>>>(f_buf, al0, ar0, el, er, N, D);
  score_stats_kernel<H_HEADS><<<cdiv(N * H, 256), 256, 0, stream>>>(row_ptr, csr_src, el, er, msum, N);
  edge_w_kernel<H_HEADS><<<cdiv(E, 256), 256, 0, stream>>>(csr_src, csr_dst, el, er, msum, exw, E);
  aggr_kernel<H_HEADS, D_HID / 2><<<cdiv(N * H * 64, 256), 256, 0, stream>>>(
      row_ptr, csr_src, exw, f_buf, nullptr, hbuf, N);
  bn_stats_kernel<<<256, C, 0, stream>>>(hbuf, bnsum, bnsq, N, C);
  bn_apply_kernel<<<cdiv(N * C, 256), 256, 0, stream>>>(hbuf, bnsum, bnsq, g0, be0, abuf, N, C);

  // ================= layer 1 =================
  gemm_mfma<<<dim3(C / 64, cdiv(N, 64)), 256, 0, stream>>>((const short*)abuf, (const short*)WT1,
                                                           f_buf, N, C, C);
  hipMemsetAsync(bnsum, 0, C * sizeof(float), stream);
  hipMemsetAsync(bnsq,  0, C * sizeof(float), stream);
  el_er_kernel<H_HEADS><<<cdiv(N * H * 64, 256), 256, 0, stream>>>(f_buf, al1, ar1, el, er, N, D);
  score_stats_kernel<H_HEADS><<<cdiv(N * H, 256), 256, 0, stream>>>(row_ptr, csr_src, el, er, msum, N);
  edge_w_kernel<H_HEADS><<<cdiv(E, 256), 256, 0, stream>>>(csr_src, csr_dst, el, er, msum, exw, E);
  aggr_kernel<H_HEADS, D_HID / 2><<<cdiv(N * H * 64, 256), 256, 0, stream>>>(
      row_ptr, csr_src, exw, f_buf, nullptr, hbuf, N);
  bn_stats_kernel<<<256, C, 0, stream>>>(hbuf, bnsum, bnsq, N, C);
  bn_apply_kernel<<<cdiv(N * C, 256), 256, 0, stream>>>(hbuf, bnsum, bnsq, g1, be1, abuf, N, C);

  // ================= layer 2 (H=1, D=40, bias fused, direct to out) =========
  gemm_mfma<<<dim3(1, cdiv(N, 64)), 256, 0, stream>>>((const short*)abuf, (const short*)WT2,
                                                      f_buf, N, C, F_OUT);
  el_er_kernel<1><<<cdiv(N * 64, 256), 256, 0, stream>>>(f_buf, al2, ar2, el, er, N, F_OUT);
  score_stats_kernel<1><<<cdiv(N, 256), 256, 0, stream>>>(row_ptr, csr_src, el, er, msum, N);
  edge_w_kernel<1><<<cdiv(E, 256), 256, 0, stream>>>(csr_src, csr_dst, el, er, msum, exw, E);
  aggr_kernel<1, F_OUT / 2><<<cdiv(N * 64, 256), 256, 0, stream>>>(
      row_ptr, csr_src, exw, f_buf, b2, out, N);
}

// Round 7
// 897.070 us; speedup vs baseline: 4.5958x; 1.1193x over previous
//
#include <hip/hip_runtime.h>
#include <hip/hip_bf16.h>

typedef __hip_bfloat16 bf16;
typedef __attribute__((ext_vector_type(8))) short short8;
typedef __attribute__((ext_vector_type(4))) float f32x4;

static constexpr int N_NODES  = 50000;
static constexpr int N_EDGES  = 800000;
static constexpr int F_IN     = 128;
static constexpr int D_HID    = 128;
static constexpr int H_HEADS  = 3;
static constexpr int F_OUT    = 40;
static constexpr float BN_EPS = 1e-5f;
static constexpr float SLOPE  = 0.2f;

__device__ __forceinline__ float bfLo(unsigned int u) { return __uint_as_float(u << 16); }
__device__ __forceinline__ float bfHi(unsigned int u) { return __uint_as_float(u & 0xffff0000u); }
__device__ __forceinline__ float bf2f(unsigned int s) { return __uint_as_float(s << 16); }

// ---------------- MFMA GEMM: C[M,Nc] = A[M,K] @ WT[Nc,K]^T, bf16 in/out -----
__global__ __launch_bounds__(256) void gemm_mfma(const short* __restrict__ A,
                                                 const short* __restrict__ WT,
                                                 bf16* __restrict__ C,
                                                 int M, int K, int Nc) {
  constexpr int BM = 64, BN = 64, BK = 64, LDP = BK + 8;
  __shared__ short As[BM * LDP];
  __shared__ short Bs[BN * LDP];
  int tid = threadIdx.x;
  int wave = tid >> 6, lane = tid & 63;
  int bm = blockIdx.y, bn = blockIdx.x;
  int lrow = tid >> 3;
  int kcol = (tid & 7) * 8;

  f32x4 acc[4];
#pragma unroll
  for (int i = 0; i < 4; ++i) acc[i] = (f32x4){0.f, 0.f, 0.f, 0.f};

  int m15 = lane & 15;
  int ksub = (lane >> 4) * 8;

  for (int k0 = 0; k0 < K; k0 += BK) {
#pragma unroll
    for (int c = 0; c < 2; ++c) {
      int r = lrow + c * 32;
      int gr = bm * BM + r; if (gr >= M) gr = M - 1;
      *(short8*)&As[r * LDP + kcol] = *(const short8*)&A[(size_t)gr * K + k0 + kcol];
      int gn = bn * BN + r;
      *(short8*)&Bs[r * LDP + kcol] = *(const short8*)&WT[(size_t)gn * K + k0 + kcol];
    }
    __syncthreads();
#pragma unroll
    for (int ks = 0; ks < BK; ks += 32) {
      short8 a = *(const short8*)&As[(wave * 16 + m15) * LDP + ks + ksub];
#pragma unroll
      for (int nb = 0; nb < 4; ++nb) {
        short8 b = *(const short8*)&Bs[(nb * 16 + m15) * LDP + ks + ksub];
        acc[nb] = __builtin_amdgcn_mfma_f32_16x16x32_bf16(a, b, acc[nb], 0, 0, 0);
      }
    }
    __syncthreads();
  }
#pragma unroll
  for (int nb = 0; nb < 4; ++nb) {
    int col = bn * BN + nb * 16 + m15;
#pragma unroll
    for (int r = 0; r < 4; ++r) {
      int row = bm * BM + wave * 16 + (lane >> 4) * 4 + r;
      if (row < M && col < Nc)
        C[(size_t)row * Nc + col] = __float2bfloat16(acc[nb][r]);
    }
  }
}

// ------------- cast fp32 -> bf16 --------------------------------------------
__global__ void cast_bf16_kernel(const float* __restrict__ in, bf16* __restrict__ out, int n) {
  for (int i = blockIdx.x * blockDim.x + threadIdx.x; i < n; i += gridDim.x * blockDim.x)
    out[i] = __float2bfloat16(in[i]);
}

// ------------- W[K,Nc] -> WT[Npad,K] bf16, zero-pad rows >= Nc --------------
__global__ void wt_build_kernel(const float* __restrict__ W, bf16* __restrict__ WT,
                                int K, int Nc, int Npad) {
  int idx = blockIdx.x * blockDim.x + threadIdx.x;
  if (idx >= Npad * K) return;
  int n = idx / K, k = idx - n * K;
  WT[idx] = __float2bfloat16(n < Nc ? W[(size_t)k * Nc + n] : 0.f);
}

// ------------- CSR build ----------------------------------------------------
__global__ void hist_kernel(const int* __restrict__ dst, int* __restrict__ cnt, int E) {
  int i = blockIdx.x * blockDim.x + threadIdx.x;
  if (i < E) atomicAdd(cnt + dst[i], 1);
}

__global__ void scan_kernel(const int* __restrict__ cnt, int* __restrict__ row_ptr,
                            int N, int E) {
  __shared__ int part[256];
  int t = threadIdx.x;
  int chunk = (N + 255) / 256;
  int b = t * chunk, e = min(b + chunk, N);
  int s = 0;
  for (int i = b; i < e; ++i) s += cnt[i];
  part[t] = s;
  __syncthreads();
  for (int off = 1; off < 256; off <<= 1) {
    int v = (t >= off) ? part[t - off] : 0;
    __syncthreads();
    part[t] += v;
    __syncthreads();
  }
  int run = (t == 0) ? 0 : part[t - 1];
  for (int i = b; i < e; ++i) { row_ptr[i] = run; run += cnt[i]; }
  if (t == 255) row_ptr[N] = E;
}

__global__ void scatter_kernel(const int* __restrict__ src, const int* __restrict__ dst,
                               const int* __restrict__ row_ptr, int* __restrict__ fill,
                               int* __restrict__ csr_src, int E) {
  int i = blockIdx.x * blockDim.x + threadIdx.x;
  if (i < E) {
    int d = dst[i];
    int pos = row_ptr[d] + atomicAdd(fill + d, 1);
    csr_src[pos] = src[i];
  }
}

// ------------- el/er: per (node,head) dot(f[n,h,:], a[h,:]) -----------------
template <int H>
__global__ void el_er_kernel(const bf16* __restrict__ f, const float* __restrict__ al,
                             const float* __restrict__ ar, float* __restrict__ el,
                             float* __restrict__ er, int N, int D) {
  int gtid = blockIdx.x * blockDim.x + threadIdx.x;
  int wave = gtid >> 6, lane = gtid & 63;
  if (wave >= N * H) return;
  int h = wave % H;
  const unsigned short* frow = (const unsigned short*)f + (size_t)wave * D;
  float sl = 0.f, sr = 0.f;
  for (int d = lane; d < D; d += 64) {
    float v = bf2f((unsigned int)frow[d]);
    sl += v * al[h * D + d];
    sr += v * ar[h * D + d];
  }
#pragma unroll
  for (int off = 32; off > 0; off >>= 1) {
    sl += __shfl_down(sl, off);
    sr += __shfl_down(sr, off);
  }
  if (lane == 0) { el[wave] = sl; er[wave] = sr; }
}

// ------------- pass A: per (dst,head) online max + 1/sum of exp -------------
template <int H>
__global__ void score_stats_kernel(const int* __restrict__ row_ptr,
                                   const int* __restrict__ csr_src,
                                   const float* __restrict__ el,
                                   const float* __restrict__ er,
                                   float2* __restrict__ msum, int N) {
  int i = blockIdx.x * blockDim.x + threadIdx.x;
  if (i >= N * H) return;
  int d = i / H, h = i - d * H;
  int beg = row_ptr[d], end = row_ptr[d + 1];
  float erd = er[i];
  float m = -1e30f, s = 0.f;
  for (int k = beg; k < end; ++k) {
    int sn = csr_src[k];
    float sc = el[sn * H + h] + erd;
    sc = sc > 0.f ? sc : SLOPE * sc;
    float mn = fmaxf(m, sc);
    s = s * __expf(m - mn) + __expf(sc - mn);
    m = mn;
  }
  msum[i] = make_float2(m, 1.f / s);
}

// ------------- fused aggregation: wave per dst, all H heads, inline w -------
// lane covers words {lane + 64*j}; for D=128 word lane+64j belongs to head j.
template <int H, int D>  // requires D == 128
__global__ __launch_bounds__(256) void aggr_fused_kernel(
    const int* __restrict__ row_ptr, const int* __restrict__ csr_src,
    const float* __restrict__ el, const float* __restrict__ er,
    const float2* __restrict__ msum, const bf16* __restrict__ f,
    float* __restrict__ out, int N) {
  constexpr int W = H * D / 2;   // words per row (192 for H=3)
  constexpr int J = W / 64;      // words per lane (3)
  int d = (blockIdx.x * 256 + threadIdx.x) >> 6;
  int lane = threadIdx.x & 63;
  if (d >= N) return;
  int beg = row_ptr[d], end = row_ptr[d + 1];
  const unsigned int* fu = (const unsigned int*)f;

  float erd[H], mh[H], ih[H];
#pragma unroll
  for (int h = 0; h < H; ++h) {
    erd[h] = er[d * H + h];
    float2 t = msum[d * H + h];
    mh[h] = t.x; ih[h] = t.y;
  }

  float aA[J][2], aB[J][2];
#pragma unroll
  for (int j = 0; j < J; ++j) { aA[j][0] = aA[j][1] = aB[j][0] = aB[j][1] = 0.f; }

  int k = beg;
  for (; k + 1 < end; k += 2) {
    int s0 = csr_src[k], s1 = csr_src[k + 1];
    float w0[H], w1[H];
#pragma unroll
    for (int h = 0; h < H; ++h) {
      float sc0 = el[s0 * H + h] + erd[h];
      sc0 = sc0 > 0.f ? sc0 : SLOPE * sc0;
      w0[h] = __expf(sc0 - mh[h]) * ih[h];
      float sc1 = el[s1 * H + h] + erd[h];
      sc1 = sc1 > 0.f ? sc1 : SLOPE * sc1;
      w1[h] = __expf(sc1 - mh[h]) * ih[h];
    }
    size_t b0 = (size_t)s0 * W, b1 = (size_t)s1 * W;
#pragma unroll
    for (int j = 0; j < J; ++j) {
      unsigned int u0 = fu[b0 + 64 * j + lane];
      unsigned int u1 = fu[b1 + 64 * j + lane];
      aA[j][0] += w0[j] * bfLo(u0);
      aA[j][1] += w0[j] * bfHi(u0);
      aB[j][0] += w1[j] * bfLo(u1);
      aB[j][1] += w1[j] * bfHi(u1);
    }
  }
  if (k < end) {
    int s0 = csr_src[k];
    float w0[H];
#pragma unroll
    for (int h = 0; h < H; ++h) {
      float sc0 = el[s0 * H + h] + erd[h];
      sc0 = sc0 > 0.f ? sc0 : SLOPE * sc0;
      w0[h] = __expf(sc0 - mh[h]) * ih[h];
    }
    size_t b0 = (size_t)s0 * W;
#pragma unroll
    for (int j = 0; j < J; ++j) {
      unsigned int u0 = fu[b0 + 64 * j + lane];
      aA[j][0] += w0[j] * bfLo(u0);
      aA[j][1] += w0[j] * bfHi(u0);
    }
  }
#pragma unroll
  for (int j = 0; j < J; ++j) {
    float2 v = make_float2(aA[j][0] + aB[j][0], aA[j][1] + aB[j][1]);
    *(float2*)&out[(size_t)d * (H * D) + 2 * (64 * j + lane)] = v;
  }
}

// ------------- output-layer aggregation: H=1, D=40, bias fused --------------
__global__ __launch_bounds__(256) void aggr_out_kernel(
    const int* __restrict__ row_ptr, const int* __restrict__ csr_src,
    const float* __restrict__ el, const float* __restrict__ er,
    const float2* __restrict__ msum, const bf16* __restrict__ f,
    const float* __restrict__ bias, float* __restrict__ out, int N) {
  constexpr int DW = F_OUT / 2;  // 20 words
  int d = (blockIdx.x * 256 + threadIdx.x) >> 6;
  int lane = threadIdx.x & 63;
  if (d >= N) return;
  int beg = row_ptr[d], end = row_ptr[d + 1];
  const unsigned int* fu = (const unsigned int*)f;
  float erd = er[d];
  float2 t = msum[d];
  float a0 = 0.f, a1 = 0.f, b0 = 0.f, b1 = 0.f;
  int k = beg;
  for (; k + 1 < end; k += 2) {
    int s0 = csr_src[k], s1 = csr_src[k + 1];
    float sc0 = el[s0] + erd; sc0 = sc0 > 0.f ? sc0 : SLOPE * sc0;
    float sc1 = el[s1] + erd; sc1 = sc1 > 0.f ? sc1 : SLOPE * sc1;
    float w0 = __expf(sc0 - t.x) * t.y;
    float w1 = __expf(sc1 - t.x) * t.y;
    if (lane < DW) {
      unsigned int u0 = fu[(size_t)s0 * DW + lane];
      unsigned int u1 = fu[(size_t)s1 * DW + lane];
      a0 += w0 * bfLo(u0); a1 += w0 * bfHi(u0);
      b0 += w1 * bfLo(u1); b1 += w1 * bfHi(u1);
    }
  }
  if (k < end) {
    int s0 = csr_src[k];
    float sc0 = el[s0] + erd; sc0 = sc0 > 0.f ? sc0 : SLOPE * sc0;
    float w0 = __expf(sc0 - t.x) * t.y;
    if (lane < DW) {
      unsigned int u0 = fu[(size_t)s0 * DW + lane];
      a0 += w0 * bfLo(u0); a1 += w0 * bfHi(u0);
    }
  }
  if (lane < DW) {
    a0 += b0 + bias[2 * lane];
    a1 += b1 + bias[2 * lane + 1];
    *(float2*)&out[(size_t)d * F_OUT + 2 * lane] = make_float2(a0, a1);
  }
}

// ------------- BN stats -----------------------------------------------------
__global__ void bn_stats_kernel(const float* __restrict__ h, float* __restrict__ sum,
                                float* __restrict__ sumsq, int N, int C) {
  int c = threadIdx.x;
  float s = 0.f, s2 = 0.f;
  for (int n = blockIdx.x; n < N; n += gridDim.x) {
    float v = h[(size_t)n * C + c];
    s += v; s2 += v * v;
  }
  atomicAdd(sum + c, s);
  atomicAdd(sumsq + c, s2);
}

// ------------- BN apply + ReLU -> bf16 --------------------------------------
__global__ void bn_apply_kernel(const float* __restrict__ h, const float* __restrict__ sum,
                                const float* __restrict__ sumsq, const float* __restrict__ g,
                                const float* __restrict__ be, bf16* __restrict__ out,
                                int N, int C) {
  int i = blockIdx.x * blockDim.x + threadIdx.x;
  if (i >= N * C) return;
  int c = i % C;
  float inv_n = 1.f / (float)N;
  float mu = sum[c] * inv_n;
  float var = sumsq[c] * inv_n - mu * mu;
  float v = (h[i] - mu) * rsqrtf(var + BN_EPS) * g[c] + be[c];
  out[i] = __float2bfloat16(v > 0.f ? v : 0.f);
}

static inline int cdiv(int a, int b) { return (a + b - 1) / b; }

extern "C" void kernel_launch(void* const* d_in, const int* in_sizes, int n_in,
                              void* d_out, int out_size, void* d_ws, size_t ws_size,
                              hipStream_t stream) {
  const float* x   = (const float*)d_in[0];
  const int* src   = (const int*)d_in[1];
  const int* dst   = (const int*)d_in[2];
  const float* W0  = (const float*)d_in[3];
  const float* al0 = (const float*)d_in[4];
  const float* ar0 = (const float*)d_in[5];
  const float* W1  = (const float*)d_in[7];
  const float* al1 = (const float*)d_in[8];
  const float* ar1 = (const float*)d_in[9];
  const float* W2  = (const float*)d_in[11];
  const float* al2 = (const float*)d_in[12];
  const float* ar2 = (const float*)d_in[13];
  const float* b2  = (const float*)d_in[14];
  const float* g0  = (const float*)d_in[15];
  const float* be0 = (const float*)d_in[16];
  const float* g1  = (const float*)d_in[17];
  const float* be1 = (const float*)d_in[18];
  float* out = (float*)d_out;

  const int N = N_NODES, E = N_EDGES, H = H_HEADS, D = D_HID;
  const int C = H * D;  // 384

  // ---- workspace carve ----
  char* p = (char*)d_ws;
  auto take = [&](size_t bytes) {
    char* r = p;
    p += (bytes + 255) & ~(size_t)255;
    return r;
  };
  bf16*   f_buf   = (bf16*) take((size_t)N * C * sizeof(bf16));
  float*  hbuf    = (float*)take((size_t)N * C * sizeof(float));
  bf16*   abuf    = (bf16*) take((size_t)N * C * sizeof(bf16));
  float*  el      = (float*)take((size_t)N * H * sizeof(float));
  float*  er      = (float*)take((size_t)N * H * sizeof(float));
  float2* msum    = (float2*)take((size_t)N * H * sizeof(float2));
  float*  bnbuf   = (float*)take((size_t)2 * C * sizeof(float));  // sum | sumsq
  bf16*   WT0     = (bf16*) take((size_t)C * F_IN * sizeof(bf16));
  bf16*   WT1     = (bf16*) take((size_t)C * C * sizeof(bf16));
  bf16*   WT2     = (bf16*) take((size_t)64 * C * sizeof(bf16));
  int*    cnt     = (int*)take((size_t)2 * N * sizeof(int));      // hist | fill
  int*    row_ptr = (int*)take((size_t)(N + 1) * sizeof(int));
  int*    csr_src = (int*)take((size_t)E * sizeof(int));
  float*  bnsum = bnbuf, *bnsq = bnbuf + C;
  int*    fill  = cnt + N;

  // ---- CSR build (by dst) ----
  hipMemsetAsync(cnt, 0, 2 * N * sizeof(int), stream);
  hist_kernel<<<cdiv(E, 256), 256, 0, stream>>>(dst, cnt, E);
  scan_kernel<<<1, 256, 0, stream>>>(cnt, row_ptr, N, E);
  scatter_kernel<<<cdiv(E, 256), 256, 0, stream>>>(src, dst, row_ptr, fill, csr_src, E);

  // ---- weight prep ----
  wt_build_kernel<<<cdiv(C * F_IN, 256), 256, 0, stream>>>(W0, WT0, F_IN, C, C);
  wt_build_kernel<<<cdiv(C * C, 256), 256, 0, stream>>>(W1, WT1, C, C, C);
  wt_build_kernel<<<cdiv(64 * C, 256), 256, 0, stream>>>(W2, WT2, C, F_OUT, 64);
  cast_bf16_kernel<<<1024, 256, 0, stream>>>(x, abuf, N * F_IN);

  // ================= layer 0 =================
  gemm_mfma<<<dim3(C / 64, cdiv(N, 64)), 256, 0, stream>>>((const short*)abuf, (const short*)WT0,
                                                           f_buf, N, F_IN, C);
  hipMemsetAsync(bnbuf, 0, 2 * C * sizeof(float), stream);
  el_er_kernel<H_HEADS><<<cdiv(N * H * 64, 256), 256, 0, stream>>>(f_buf, al0, ar0, el, er, N, D);
  score_stats_kernel<H_HEADS><<<cdiv(N * H, 256), 256, 0, stream>>>(row_ptr, csr_src, el, er, msum, N);
  aggr_fused_kernel<H_HEADS, D_HID><<<cdiv(N * 64, 256), 256, 0, stream>>>(
      row_ptr, csr_src, el, er, msum, f_buf, hbuf, N);
  bn_stats_kernel<<<256, C, 0, stream>>>(hbuf, bnsum, bnsq, N, C);
  bn_apply_kernel<<<cdiv(N * C, 256), 256, 0, stream>>>(hbuf, bnsum, bnsq, g0, be0, abuf, N, C);

  // ================= layer 1 =================
  gemm_mfma<<<dim3(C / 64, cdiv(N, 64)), 256, 0, stream>>>((const short*)abuf, (const short*)WT1,
                                                           f_buf, N, C, C);
  hipMemsetAsync(bnbuf, 0, 2 * C * sizeof(float), stream);
  el_er_kernel<H_HEADS><<<cdiv(N * H * 64, 256), 256, 0, stream>>>(f_buf, al1, ar1, el, er, N, D);
  score_stats_kernel<H_HEADS><<<cdiv(N * H, 256), 256, 0, stream>>>(row_ptr, csr_src, el, er, msum, N);
  aggr_fused_kernel<H_HEADS, D_HID><<<cdiv(N * 64, 256), 256, 0, stream>>>(
      row_ptr, csr_src, el, er, msum, f_buf, hbuf, N);
  bn_stats_kernel<<<256, C, 0, stream>>>(hbuf, bnsum, bnsq, N, C);
  bn_apply_kernel<<<cdiv(N * C, 256), 256, 0, stream>>>(hbuf, bnsum, bnsq, g1, be1, abuf, N, C);

  // ================= layer 2 (H=1, D=40, bias fused, direct to out) =========
  gemm_mfma<<<dim3(1, cdiv(N, 64)), 256, 0, stream>>>((const short*)abuf, (const short*)WT2,
                                                      f_buf, N, C, F_OUT);
  el_er_kernel<1><<<cdiv(N * 64, 256), 256, 0, stream>>>(f_buf, al2, ar2, el, er, N, F_OUT);
  score_stats_kernel<1><<<cdiv(N, 256), 256, 0, stream>>>(row_ptr, csr_src, el, er, msum, N);
  aggr_out_kernel<<<cdiv(N * 64, 256), 256, 0, stream>>>(
      row_ptr, csr_src, el, er, msum, f_buf, b2, out, N);
}

// Round 8
// 849.765 us; speedup vs baseline: 4.8517x; 1.0557x over previous
//
#include <hip/hip_runtime.h>
#include <hip/hip_bf16.h>

typedef __hip_bfloat16 bf16;
typedef __attribute__((ext_vector_type(8))) short short8;
typedef __attribute__((ext_vector_type(4))) float f32x4;

static constexpr int N_NODES  = 50000;
static constexpr int N_EDGES  = 800000;
static constexpr int F_IN     = 128;
static constexpr int D_HID    = 128;
static constexpr int H_HEADS  = 3;
static constexpr int F_OUT    = 40;
static constexpr float BN_EPS = 1e-5f;
static constexpr float SLOPE  = 0.2f;

__device__ __forceinline__ float bfLo(unsigned int u) { return __uint_as_float(u << 16); }
__device__ __forceinline__ float bfHi(unsigned int u) { return __uint_as_float(u & 0xffff0000u); }

// ---------------- MFMA GEMM: C[M,Nc] = A[M,K] @ WT[Nc,K]^T, bf16 in/out -----
__global__ __launch_bounds__(256) void gemm_mfma(const short* __restrict__ A,
                                                 const short* __restrict__ WT,
                                                 bf16* __restrict__ C,
                                                 int M, int K, int Nc) {
  constexpr int BM = 64, BN = 64, BK = 64, LDP = BK + 8;
  __shared__ short As[BM * LDP];
  __shared__ short Bs[BN * LDP];
  int tid = threadIdx.x;
  int wave = tid >> 6, lane = tid & 63;
  int bm = blockIdx.y, bn = blockIdx.x;
  int lrow = tid >> 3;
  int kcol = (tid & 7) * 8;

  f32x4 acc[4];
#pragma unroll
  for (int i = 0; i < 4; ++i) acc[i] = (f32x4){0.f, 0.f, 0.f, 0.f};

  int m15 = lane & 15;
  int ksub = (lane >> 4) * 8;

  for (int k0 = 0; k0 < K; k0 += BK) {
#pragma unroll
    for (int c = 0; c < 2; ++c) {
      int r = lrow + c * 32;
      int gr = bm * BM + r; if (gr >= M) gr = M - 1;
      *(short8*)&As[r * LDP + kcol] = *(const short8*)&A[(size_t)gr * K + k0 + kcol];
      int gn = bn * BN + r;
      *(short8*)&Bs[r * LDP + kcol] = *(const short8*)&WT[(size_t)gn * K + k0 + kcol];
    }
    __syncthreads();
#pragma unroll
    for (int ks = 0; ks < BK; ks += 32) {
      short8 a = *(const short8*)&As[(wave * 16 + m15) * LDP + ks + ksub];
#pragma unroll
      for (int nb = 0; nb < 4; ++nb) {
        short8 b = *(const short8*)&Bs[(nb * 16 + m15) * LDP + ks + ksub];
        acc[nb] = __builtin_amdgcn_mfma_f32_16x16x32_bf16(a, b, acc[nb], 0, 0, 0);
      }
    }
    __syncthreads();
  }
#pragma unroll
  for (int nb = 0; nb < 4; ++nb) {
    int col = bn * BN + nb * 16 + m15;
#pragma unroll
    for (int r = 0; r < 4; ++r) {
      int row = bm * BM + wave * 16 + (lane >> 4) * 4 + r;
      if (row < M && col < Nc)
        C[(size_t)row * Nc + col] = __float2bfloat16(acc[nb][r]);
    }
  }
}

// ------------- cast fp32 -> bf16 --------------------------------------------
__global__ void cast_bf16_kernel(const float* __restrict__ in, bf16* __restrict__ out, int n) {
  for (int i = blockIdx.x * blockDim.x + threadIdx.x; i < n; i += gridDim.x * blockDim.x)
    out[i] = __float2bfloat16(in[i]);
}

// ------------- W[K,Nc] -> WT[Npad,K] bf16, zero-pad rows >= Nc --------------
__global__ void wt_build_kernel(const float* __restrict__ W, bf16* __restrict__ WT,
                                int K, int Nc, int Npad) {
  int idx = blockIdx.x * blockDim.x + threadIdx.x;
  if (idx >= Npad * K) return;
  int n = idx / K, k = idx - n * K;
  WT[idx] = __float2bfloat16(n < Nc ? W[(size_t)k * Nc + n] : 0.f);
}

// ------------- CSR build ----------------------------------------------------
__global__ void hist_kernel(const int* __restrict__ dst, int* __restrict__ cnt, int E) {
  int i = blockIdx.x * blockDim.x + threadIdx.x;
  if (i < E) atomicAdd(cnt + dst[i], 1);
}

__global__ void scan_kernel(const int* __restrict__ cnt, int* __restrict__ row_ptr,
                            int N, int E) {
  __shared__ int part[256];
  int t = threadIdx.x;
  int chunk = (N + 255) / 256;
  int b = t * chunk, e = min(b + chunk, N);
  int s = 0;
  for (int i = b; i < e; ++i) s += cnt[i];
  part[t] = s;
  __syncthreads();
  for (int off = 1; off < 256; off <<= 1) {
    int v = (t >= off) ? part[t - off] : 0;
    __syncthreads();
    part[t] += v;
    __syncthreads();
  }
  int run = (t == 0) ? 0 : part[t - 1];
  for (int i = b; i < e; ++i) { row_ptr[i] = run; run += cnt[i]; }
  if (t == 255) row_ptr[N] = E;
}

__global__ void scatter_kernel(const int* __restrict__ src, const int* __restrict__ dst,
                               const int* __restrict__ row_ptr, int* __restrict__ fill,
                               int* __restrict__ csr_src, int E) {
  int i = blockIdx.x * blockDim.x + threadIdx.x;
  if (i < E) {
    int d = dst[i];
    int pos = row_ptr[d] + atomicAdd(fill + d, 1);
    csr_src[pos] = src[i];
  }
}

// ------------- el/er: per (node,head) dot(f[n,h,:], a[h,:]) -----------------
// ELS = stride of el writes (4 for packed float4 layout, 1 for layer 2)
template <int H, int ELS>
__global__ void el_er_kernel(const bf16* __restrict__ f, const float* __restrict__ al,
                             const float* __restrict__ ar, float* __restrict__ el,
                             float* __restrict__ er, int N, int D) {
  int gtid = blockIdx.x * blockDim.x + threadIdx.x;
  int wave = gtid >> 6, lane = gtid & 63;
  if (wave >= N * H) return;
  int n = wave / H, h = wave - n * H;
  const unsigned short* frow = (const unsigned short*)f + (size_t)wave * D;
  float sl = 0.f, sr = 0.f;
  for (int d = lane; d < D; d += 64) {
    float v = __uint_as_float(((unsigned int)frow[d]) << 16);
    sl += v * al[h * D + d];
    sr += v * ar[h * D + d];
  }
#pragma unroll
  for (int off = 32; off > 0; off >>= 1) {
    sl += __shfl_down(sl, off);
    sr += __shfl_down(sr, off);
  }
  if (lane == 0) { el[n * ELS + h] = sl; er[n * H + h] = sr; }
}

// ------------- fused aggregation: wave per dst, no-max softmax inline -------
// Lane-batched weights: each lane computes w for one edge of the chunk, then
// shuffle-broadcast. Word group j (64 words) == head j (requires D == 128).
template <int H, int D>
__global__ __launch_bounds__(256) void aggr_fused_kernel(
    const int* __restrict__ row_ptr, const int* __restrict__ csr_src,
    const float4* __restrict__ el4, const float* __restrict__ er,
    const bf16* __restrict__ f, float* __restrict__ out, int N) {
  constexpr int W = H * D / 2;   // words per row (192)
  constexpr int J = W / 64;      // words per lane (3) == H
  int d = (blockIdx.x * 256 + threadIdx.x) >> 6;
  int lane = threadIdx.x & 63;
  if (d >= N) return;
  int beg = row_ptr[d], end = row_ptr[d + 1];
  const unsigned int* fu = (const unsigned int*)f;

  float erd[H];
#pragma unroll
  for (int h = 0; h < H; ++h) erd[h] = er[d * H + h];
  float acc[J][2];
#pragma unroll
  for (int j = 0; j < J; ++j) acc[j][0] = acc[j][1] = 0.f;
  float sp[H];
#pragma unroll
  for (int h = 0; h < H; ++h) sp[h] = 0.f;

  for (int k0 = beg; k0 < end; k0 += 64) {
    int nk = end - k0; if (nk > 64) nk = 64;
    int s_l = 0;
    float w_l[H];
#pragma unroll
    for (int h = 0; h < H; ++h) w_l[h] = 0.f;
    if (lane < nk) {
      s_l = csr_src[k0 + lane];
      float4 e4 = el4[s_l];
      float ev[3] = {e4.x, e4.y, e4.z};
#pragma unroll
      for (int h = 0; h < H; ++h) {
        float sc = ev[h] + erd[h];
        sc = sc > 0.f ? sc : SLOPE * sc;
        float w = __expf(sc);
        w_l[h] = w;
        sp[h] += w;
      }
    }
    for (int e = 0; e < nk; ++e) {
      int se = __shfl(s_l, e);
      float wh[H];
#pragma unroll
      for (int h = 0; h < H; ++h) wh[h] = __shfl(w_l[h], e);
      size_t b = (size_t)se * W;
#pragma unroll
      for (int j = 0; j < J; ++j) {
        unsigned int u = fu[b + 64 * j + lane];
        acc[j][0] += wh[j] * bfLo(u);
        acc[j][1] += wh[j] * bfHi(u);
      }
    }
  }
#pragma unroll
  for (int h = 0; h < H; ++h) {
#pragma unroll
    for (int off = 32; off > 0; off >>= 1) sp[h] += __shfl_xor(sp[h], off);
  }
#pragma unroll
  for (int j = 0; j < J; ++j) {
    float inv = 1.f / sp[j];
    *(float2*)&out[(size_t)d * (H * D) + 2 * (64 * j + lane)] =
        make_float2(acc[j][0] * inv, acc[j][1] * inv);
  }
}

// ------------- output-layer aggregation: H=1, D=40, bias fused --------------
__global__ __launch_bounds__(256) void aggr_out_kernel(
    const int* __restrict__ row_ptr, const int* __restrict__ csr_src,
    const float* __restrict__ el, const float* __restrict__ er,
    const bf16* __restrict__ f, const float* __restrict__ bias,
    float* __restrict__ out, int N) {
  constexpr int DW = F_OUT / 2;  // 20 words
  int d = (blockIdx.x * 256 + threadIdx.x) >> 6;
  int lane = threadIdx.x & 63;
  if (d >= N) return;
  int beg = row_ptr[d], end = row_ptr[d + 1];
  const unsigned int* fu = (const unsigned int*)f;
  float erd = er[d];
  float a0 = 0.f, a1 = 0.f, sp = 0.f;
  for (int k0 = beg; k0 < end; k0 += 64) {
    int nk = end - k0; if (nk > 64) nk = 64;
    int s_l = 0; float w_l = 0.f;
    if (lane < nk) {
      s_l = csr_src[k0 + lane];
      float sc = el[s_l] + erd;
      sc = sc > 0.f ? sc : SLOPE * sc;
      w_l = __expf(sc);
      sp += w_l;
    }
    for (int e = 0; e < nk; ++e) {
      int se = __shfl(s_l, e);
      float w = __shfl(w_l, e);
      if (lane < DW) {
        unsigned int u = fu[(size_t)se * DW + lane];
        a0 += w * bfLo(u);
        a1 += w * bfHi(u);
      }
    }
  }
#pragma unroll
  for (int off = 32; off > 0; off >>= 1) sp += __shfl_xor(sp, off);
  if (lane < DW) {
    float inv = 1.f / sp;
    *(float2*)&out[(size_t)d * F_OUT + 2 * lane] =
        make_float2(a0 * inv + bias[2 * lane], a1 * inv + bias[2 * lane + 1]);
  }
}

// ------------- BN stats -----------------------------------------------------
__global__ void bn_stats_kernel(const float* __restrict__ h, float* __restrict__ sum,
                                float* __restrict__ sumsq, int N, int C) {
  int c = threadIdx.x;
  float s = 0.f, s2 = 0.f;
  for (int n = blockIdx.x; n < N; n += gridDim.x) {
    float v = h[(size_t)n * C + c];
    s += v; s2 += v * v;
  }
  atomicAdd(sum + c, s);
  atomicAdd(sumsq + c, s2);
}

// ------------- BN apply + ReLU -> bf16 --------------------------------------
__global__ void bn_apply_kernel(const float* __restrict__ h, const float* __restrict__ sum,
                                const float* __restrict__ sumsq, const float* __restrict__ g,
                                const float* __restrict__ be, bf16* __restrict__ out,
                                int N, int C) {
  int i = blockIdx.x * blockDim.x + threadIdx.x;
  if (i >= N * C) return;
  int c = i % C;
  float inv_n = 1.f / (float)N;
  float mu = sum[c] * inv_n;
  float var = sumsq[c] * inv_n - mu * mu;
  float v = (h[i] - mu) * rsqrtf(var + BN_EPS) * g[c] + be[c];
  out[i] = __float2bfloat16(v > 0.f ? v : 0.f);
}

static inline int cdiv(int a, int b) { return (a + b - 1) / b; }

extern "C" void kernel_launch(void* const* d_in, const int* in_sizes, int n_in,
                              void* d_out, int out_size, void* d_ws, size_t ws_size,
                              hipStream_t stream) {
  const float* x   = (const float*)d_in[0];
  const int* src   = (const int*)d_in[1];
  const int* dst   = (const int*)d_in[2];
  const float* W0  = (const float*)d_in[3];
  const float* al0 = (const float*)d_in[4];
  const float* ar0 = (const float*)d_in[5];
  const float* W1  = (const float*)d_in[7];
  const float* al1 = (const float*)d_in[8];
  const float* ar1 = (const float*)d_in[9];
  const float* W2  = (const float*)d_in[11];
  const float* al2 = (const float*)d_in[12];
  const float* ar2 = (const float*)d_in[13];
  const float* b2  = (const float*)d_in[14];
  const float* g0  = (const float*)d_in[15];
  const float* be0 = (const float*)d_in[16];
  const float* g1  = (const float*)d_in[17];
  const float* be1 = (const float*)d_in[18];
  float* out = (float*)d_out;

  const int N = N_NODES, E = N_EDGES, H = H_HEADS, D = D_HID;
  const int C = H * D;  // 384

  // ---- workspace carve ----
  char* p = (char*)d_ws;
  auto take = [&](size_t bytes) {
    char* r = p;
    p += (bytes + 255) & ~(size_t)255;
    return r;
  };
  bf16*   f_buf   = (bf16*) take((size_t)N * C * sizeof(bf16));
  float*  hbuf    = (float*)take((size_t)N * C * sizeof(float));
  bf16*   abuf    = (bf16*) take((size_t)N * C * sizeof(bf16));
  float*  elbuf   = (float*)take((size_t)N * 4 * sizeof(float));  // packed float4 (layers 0/1) or plain (layer 2)
  float*  er      = (float*)take((size_t)N * H * sizeof(float));
  float*  bnbuf   = (float*)take((size_t)2 * C * sizeof(float));  // sum | sumsq
  bf16*   WT0     = (bf16*) take((size_t)C * F_IN * sizeof(bf16));
  bf16*   WT1     = (bf16*) take((size_t)C * C * sizeof(bf16));
  bf16*   WT2     = (bf16*) take((size_t)64 * C * sizeof(bf16));
  int*    cnt     = (int*)take((size_t)2 * N * sizeof(int));      // hist | fill
  int*    row_ptr = (int*)take((size_t)(N + 1) * sizeof(int));
  int*    csr_src = (int*)take((size_t)E * sizeof(int));
  float*  bnsum = bnbuf, *bnsq = bnbuf + C;
  int*    fill  = cnt + N;

  // ---- CSR build (by dst) ----
  hipMemsetAsync(cnt, 0, 2 * N * sizeof(int), stream);
  hist_kernel<<<cdiv(E, 256), 256, 0, stream>>>(dst, cnt, E);
  scan_kernel<<<1, 256, 0, stream>>>(cnt, row_ptr, N, E);
  scatter_kernel<<<cdiv(E, 256), 256, 0, stream>>>(src, dst, row_ptr, fill, csr_src, E);

  // ---- weight prep ----
  wt_build_kernel<<<cdiv(C * F_IN, 256), 256, 0, stream>>>(W0, WT0, F_IN, C, C);
  wt_build_kernel<<<cdiv(C * C, 256), 256, 0, stream>>>(W1, WT1, C, C, C);
  wt_build_kernel<<<cdiv(64 * C, 256), 256, 0, stream>>>(W2, WT2, C, F_OUT, 64);
  cast_bf16_kernel<<<1024, 256, 0, stream>>>(x, abuf, N * F_IN);

  // ================= layer 0 =================
  gemm_mfma<<<dim3(C / 64, cdiv(N, 64)), 256, 0, stream>>>((const short*)abuf, (const short*)WT0,
                                                           f_buf, N, F_IN, C);
  hipMemsetAsync(bnbuf, 0, 2 * C * sizeof(float), stream);
  el_er_kernel<H_HEADS, 4><<<cdiv(N * H * 64, 256), 256, 0, stream>>>(f_buf, al0, ar0, elbuf, er, N, D);
  aggr_fused_kernel<H_HEADS, D_HID><<<cdiv(N * 64, 256), 256, 0, stream>>>(
      row_ptr, csr_src, (const float4*)elbuf, er, f_buf, hbuf, N);
  bn_stats_kernel<<<256, C, 0, stream>>>(hbuf, bnsum, bnsq, N, C);
  bn_apply_kernel<<<cdiv(N * C, 256), 256, 0, stream>>>(hbuf, bnsum, bnsq, g0, be0, abuf, N, C);

  // ================= layer 1 =================
  gemm_mfma<<<dim3(C / 64, cdiv(N, 64)), 256, 0, stream>>>((const short*)abuf, (const short*)WT1,
                                                           f_buf, N, C, C);
  hipMemsetAsync(bnbuf, 0, 2 * C * sizeof(float), stream);
  el_er_kernel<H_HEADS, 4><<<cdiv(N * H * 64, 256), 256, 0, stream>>>(f_buf, al1, ar1, elbuf, er, N, D);
  aggr_fused_kernel<H_HEADS, D_HID><<<cdiv(N * 64, 256), 256, 0, stream>>>(
      row_ptr, csr_src, (const float4*)elbuf, er, f_buf, hbuf, N);
  bn_stats_kernel<<<256, C, 0, stream>>>(hbuf, bnsum, bnsq, N, C);
  bn_apply_kernel<<<cdiv(N * C, 256), 256, 0, stream>>>(hbuf, bnsum, bnsq, g1, be1, abuf, N, C);

  // ================= layer 2 (H=1, D=40, bias fused, direct to out) =========
  gemm_mfma<<<dim3(1, cdiv(N, 64)), 256, 0, stream>>>((const short*)abuf, (const short*)WT2,
                                                      f_buf, N, C, F_OUT);
  el_er_kernel<1, 1><<<cdiv(N * 64, 256), 256, 0, stream>>>(f_buf, al2, ar2, elbuf, er, N, F_OUT);
  aggr_out_kernel<<<cdiv(N * 64, 256), 256, 0, stream>>>(
      row_ptr, csr_src, elbuf, er, f_buf, b2, out, N);
}

// Round 9
// 813.887 us; speedup vs baseline: 5.0656x; 1.0441x over previous
//
#include <hip/hip_runtime.h>
#include <hip/hip_bf16.h>

typedef __hip_bfloat16 bf16;
typedef __attribute__((ext_vector_type(8))) short short8;
typedef __attribute__((ext_vector_type(4))) float f32x4;

static constexpr int N_NODES  = 50000;
static constexpr int N_EDGES  = 800000;
static constexpr int F_IN     = 128;
static constexpr int D_HID    = 128;
static constexpr int H_HEADS  = 3;
static constexpr int F_OUT    = 40;
static constexpr float BN_EPS = 1e-5f;
static constexpr float SLOPE  = 0.2f;

__device__ __forceinline__ float bfLo(unsigned int u) { return __uint_as_float(u << 16); }
__device__ __forceinline__ float bfHi(unsigned int u) { return __uint_as_float(u & 0xffff0000u); }

// ---------------- MFMA GEMM + fused el/er epilogue --------------------------
// C[M,Nc] = A[M,K] @ WT[Nc,K]^T (bf16 in/out). Epilogue: for each row,
// el[row*els+h] += sum_cols acc*alp[col]; er[row*ers+h] += sum_cols acc*arp[col]
// h = (bn*64)>>7 (one head per 64-col block). alp/arp zero-padded past Nc.
__global__ __launch_bounds__(256) void gemm_mfma(const short* __restrict__ A,
                                                 const short* __restrict__ WT,
                                                 bf16* __restrict__ C,
                                                 const float* __restrict__ alp,
                                                 const float* __restrict__ arp,
                                                 float* __restrict__ el,
                                                 float* __restrict__ er,
                                                 int M, int K, int Nc, int els, int ers) {
  constexpr int BM = 64, BN = 64, BK = 64, LDP = BK + 8;
  __shared__ short As[BM * LDP];
  __shared__ short Bs[BN * LDP];
  int tid = threadIdx.x;
  int wave = tid >> 6, lane = tid & 63;
  int bm = blockIdx.y, bn = blockIdx.x;
  int lrow = tid >> 3;
  int kcol = (tid & 7) * 8;

  f32x4 acc[4];
#pragma unroll
  for (int i = 0; i < 4; ++i) acc[i] = (f32x4){0.f, 0.f, 0.f, 0.f};

  int m15 = lane & 15;
  int ksub = (lane >> 4) * 8;

  for (int k0 = 0; k0 < K; k0 += BK) {
#pragma unroll
    for (int c = 0; c < 2; ++c) {
      int r = lrow + c * 32;
      int gr = bm * BM + r; if (gr >= M) gr = M - 1;
      *(short8*)&As[r * LDP + kcol] = *(const short8*)&A[(size_t)gr * K + k0 + kcol];
      int gn = bn * BN + r;
      *(short8*)&Bs[r * LDP + kcol] = *(const short8*)&WT[(size_t)gn * K + k0 + kcol];
    }
    __syncthreads();
#pragma unroll
    for (int ks = 0; ks < BK; ks += 32) {
      short8 a = *(const short8*)&As[(wave * 16 + m15) * LDP + ks + ksub];
#pragma unroll
      for (int nb = 0; nb < 4; ++nb) {
        short8 b = *(const short8*)&Bs[(nb * 16 + m15) * LDP + ks + ksub];
        acc[nb] = __builtin_amdgcn_mfma_f32_16x16x32_bf16(a, b, acc[nb], 0, 0, 0);
      }
    }
    __syncthreads();
  }

  int h = (bn * 64) >> 7;
  float alv[4], arv[4];
#pragma unroll
  for (int nb = 0; nb < 4; ++nb) {
    int col = bn * BN + nb * 16 + m15;
    alv[nb] = alp[col];
    arv[nb] = arp[col];
  }
#pragma unroll
  for (int r = 0; r < 4; ++r) {
    int row = bm * BM + wave * 16 + (lane >> 4) * 4 + r;
    float pe = 0.f, pr = 0.f;
#pragma unroll
    for (int nb = 0; nb < 4; ++nb) {
      float v = acc[nb][r];
      pe += v * alv[nb];
      pr += v * arv[nb];
      int col = bn * BN + nb * 16 + m15;
      if (row < M && col < Nc)
        C[(size_t)row * Nc + col] = __float2bfloat16(v);
    }
#pragma unroll
    for (int off = 1; off < 16; off <<= 1) {
      pe += __shfl_xor(pe, off);
      pr += __shfl_xor(pr, off);
    }
    if (m15 == 0 && row < M) {
      atomicAdd(&el[(size_t)row * els + h], pe);
      atomicAdd(&er[(size_t)row * ers + h], pr);
    }
  }
}

// ------------- prep: cast x, build WT0/1/2, pad al2/ar2, zero cnt/el/er -----
__global__ void prep_kernel(const float* __restrict__ x, bf16* __restrict__ abuf,
                            const float* __restrict__ W0, const float* __restrict__ W1,
                            const float* __restrict__ W2, bf16* __restrict__ WT0,
                            bf16* __restrict__ WT1, bf16* __restrict__ WT2,
                            const float* __restrict__ al2, const float* __restrict__ ar2,
                            float* __restrict__ alp2, float* __restrict__ arp2,
                            int* __restrict__ cnt, float* __restrict__ elbuf,
                            float* __restrict__ er) {
  const int NTOT = N_NODES * F_IN;  // 6.4M
  for (int i = blockIdx.x * blockDim.x + threadIdx.x; i < NTOT;
       i += gridDim.x * blockDim.x) {
    abuf[i] = __float2bfloat16(x[i]);
    if (i < 384 * 384) { int n = i / 384, k = i - n * 384; WT1[i] = __float2bfloat16(W1[(size_t)k * 384 + n]); }
    if (i < 384 * 128) { int n = i / 128, k = i - n * 128; WT0[i] = __float2bfloat16(W0[(size_t)k * 384 + n]); }
    if (i < 64 * 384)  { int n = i / 384, k = i - n * 384; WT2[i] = __float2bfloat16(n < F_OUT ? W2[(size_t)k * F_OUT + n] : 0.f); }
    if (i < 2 * N_NODES) cnt[i] = 0;
    if (i < 4 * N_NODES) elbuf[i] = 0.f;
    if (i < 3 * N_NODES) er[i] = 0.f;
    if (i < 64) { alp2[i] = i < F_OUT ? al2[i] : 0.f; arp2[i] = i < F_OUT ? ar2[i] : 0.f; }
  }
}

// ------------- CSR build ----------------------------------------------------
__global__ void hist_kernel(const int* __restrict__ dst, int* __restrict__ cnt, int E) {
  int i = blockIdx.x * blockDim.x + threadIdx.x;
  if (i < E) atomicAdd(cnt + dst[i], 1);
}

__global__ void scan_kernel(const int* __restrict__ cnt, int* __restrict__ row_ptr,
                            int N, int E) {
  __shared__ int part[256];
  int t = threadIdx.x;
  int chunk = (N + 255) / 256;
  int b = t * chunk, e = min(b + chunk, N);
  int s = 0;
  for (int i = b; i < e; ++i) s += cnt[i];
  part[t] = s;
  __syncthreads();
  for (int off = 1; off < 256; off <<= 1) {
    int v = (t >= off) ? part[t - off] : 0;
    __syncthreads();
    part[t] += v;
    __syncthreads();
  }
  int run = (t == 0) ? 0 : part[t - 1];
  for (int i = b; i < e; ++i) { row_ptr[i] = run; run += cnt[i]; }
  if (t == 255) row_ptr[N] = E;
}

__global__ void scatter_kernel(const int* __restrict__ src, const int* __restrict__ dst,
                               const int* __restrict__ row_ptr, int* __restrict__ fill,
                               int* __restrict__ csr_src, int E) {
  int i = blockIdx.x * blockDim.x + threadIdx.x;
  if (i < E) {
    int d = dst[i];
    int pos = row_ptr[d] + atomicAdd(fill + d, 1);
    csr_src[pos] = src[i];
  }
}

// ------------- fused aggregation: wave per dst, no-max softmax inline -------
template <int H, int D>
__global__ __launch_bounds__(256) void aggr_fused_kernel(
    const int* __restrict__ row_ptr, const int* __restrict__ csr_src,
    const float4* __restrict__ el4, const float* __restrict__ er,
    const bf16* __restrict__ f, float* __restrict__ out,
    float* __restrict__ bnzero, int N) {
  if (blockIdx.x == 0) {
    for (int j = threadIdx.x; j < 2 * H * D; j += 256) bnzero[j] = 0.f;
  }
  constexpr int W = H * D / 2;   // words per row (192)
  constexpr int J = W / 64;      // words per lane (3) == H
  int d = (blockIdx.x * 256 + threadIdx.x) >> 6;
  int lane = threadIdx.x & 63;
  if (d >= N) return;
  int beg = row_ptr[d], end = row_ptr[d + 1];
  const unsigned int* fu = (const unsigned int*)f;

  float erd[H];
#pragma unroll
  for (int h = 0; h < H; ++h) erd[h] = er[d * H + h];
  float acc[J][2];
#pragma unroll
  for (int j = 0; j < J; ++j) acc[j][0] = acc[j][1] = 0.f;
  float sp[H];
#pragma unroll
  for (int h = 0; h < H; ++h) sp[h] = 0.f;

  for (int k0 = beg; k0 < end; k0 += 64) {
    int nk = end - k0; if (nk > 64) nk = 64;
    int s_l = 0;
    float w_l[H];
#pragma unroll
    for (int h = 0; h < H; ++h) w_l[h] = 0.f;
    if (lane < nk) {
      s_l = csr_src[k0 + lane];
      float4 e4 = el4[s_l];
      float ev[3] = {e4.x, e4.y, e4.z};
#pragma unroll
      for (int h = 0; h < H; ++h) {
        float sc = ev[h] + erd[h];
        sc = sc > 0.f ? sc : SLOPE * sc;
        float w = __expf(sc);
        w_l[h] = w;
        sp[h] += w;
      }
    }
    for (int e = 0; e < nk; ++e) {
      int se = __shfl(s_l, e);
      float wh[H];
#pragma unroll
      for (int h = 0; h < H; ++h) wh[h] = __shfl(w_l[h], e);
      size_t b = (size_t)se * W;
#pragma unroll
      for (int j = 0; j < J; ++j) {
        unsigned int u = fu[b + 64 * j + lane];
        acc[j][0] += wh[j] * bfLo(u);
        acc[j][1] += wh[j] * bfHi(u);
      }
    }
  }
#pragma unroll
  for (int h = 0; h < H; ++h) {
#pragma unroll
    for (int off = 32; off > 0; off >>= 1) sp[h] += __shfl_xor(sp[h], off);
  }
#pragma unroll
  for (int j = 0; j < J; ++j) {
    float inv = 1.f / sp[j];
    *(float2*)&out[(size_t)d * (H * D) + 2 * (64 * j + lane)] =
        make_float2(acc[j][0] * inv, acc[j][1] * inv);
  }
}

// ------------- output-layer aggregation: H=1, D=40, bias fused --------------
__global__ __launch_bounds__(256) void aggr_out_kernel(
    const int* __restrict__ row_ptr, const int* __restrict__ csr_src,
    const float* __restrict__ el, const float* __restrict__ er,
    const bf16* __restrict__ f, const float* __restrict__ bias,
    float* __restrict__ out, int N) {
  constexpr int DW = F_OUT / 2;  // 20 words
  int d = (blockIdx.x * 256 + threadIdx.x) >> 6;
  int lane = threadIdx.x & 63;
  if (d >= N) return;
  int beg = row_ptr[d], end = row_ptr[d + 1];
  const unsigned int* fu = (const unsigned int*)f;
  float erd = er[d];
  float a0 = 0.f, a1 = 0.f, sp = 0.f;
  for (int k0 = beg; k0 < end; k0 += 64) {
    int nk = end - k0; if (nk > 64) nk = 64;
    int s_l = 0; float w_l = 0.f;
    if (lane < nk) {
      s_l = csr_src[k0 + lane];
      float sc = el[s_l] + erd;
      sc = sc > 0.f ? sc : SLOPE * sc;
      w_l = __expf(sc);
      sp += w_l;
    }
    for (int e = 0; e < nk; ++e) {
      int se = __shfl(s_l, e);
      float w = __shfl(w_l, e);
      if (lane < DW) {
        unsigned int u = fu[(size_t)se * DW + lane];
        a0 += w * bfLo(u);
        a1 += w * bfHi(u);
      }
    }
  }
#pragma unroll
  for (int off = 32; off > 0; off >>= 1) sp += __shfl_xor(sp, off);
  if (lane < DW) {
    float inv = 1.f / sp;
    *(float2*)&out[(size_t)d * F_OUT + 2 * lane] =
        make_float2(a0 * inv + bias[2 * lane], a1 * inv + bias[2 * lane + 1]);
  }
}

// ------------- BN stats -----------------------------------------------------
__global__ void bn_stats_kernel(const float* __restrict__ h, float* __restrict__ sum,
                                float* __restrict__ sumsq, int N, int C) {
  int c = threadIdx.x;
  float s = 0.f, s2 = 0.f;
  for (int n = blockIdx.x; n < N; n += gridDim.x) {
    float v = h[(size_t)n * C + c];
    s += v; s2 += v * v;
  }
  atomicAdd(sum + c, s);
  atomicAdd(sumsq + c, s2);
}

// ------------- BN apply + ReLU -> bf16; zeroes el/er for next layer ---------
__global__ void bn_apply_kernel(const float* __restrict__ h, const float* __restrict__ sum,
                                const float* __restrict__ sumsq, const float* __restrict__ g,
                                const float* __restrict__ be, bf16* __restrict__ out,
                                float* __restrict__ elz, float* __restrict__ erz,
                                int N, int C) {
  int i = blockIdx.x * blockDim.x + threadIdx.x;
  if (i < 4 * N) elz[i] = 0.f;
  if (i < 3 * N) erz[i] = 0.f;
  if (i >= N * C) return;
  int c = i % C;
  float inv_n = 1.f / (float)N;
  float mu = sum[c] * inv_n;
  float var = sumsq[c] * inv_n - mu * mu;
  float v = (h[i] - mu) * rsqrtf(var + BN_EPS) * g[c] + be[c];
  out[i] = __float2bfloat16(v > 0.f ? v : 0.f);
}

static inline int cdiv(int a, int b) { return (a + b - 1) / b; }

extern "C" void kernel_launch(void* const* d_in, const int* in_sizes, int n_in,
                              void* d_out, int out_size, void* d_ws, size_t ws_size,
                              hipStream_t stream) {
  const float* x   = (const float*)d_in[0];
  const int* src   = (const int*)d_in[1];
  const int* dst   = (const int*)d_in[2];
  const float* W0  = (const float*)d_in[3];
  const float* al0 = (const float*)d_in[4];
  const float* ar0 = (const float*)d_in[5];
  const float* W1  = (const float*)d_in[7];
  const float* al1 = (const float*)d_in[8];
  const float* ar1 = (const float*)d_in[9];
  const float* W2  = (const float*)d_in[11];
  const float* al2 = (const float*)d_in[12];
  const float* ar2 = (const float*)d_in[13];
  const float* b2  = (const float*)d_in[14];
  const float* g0  = (const float*)d_in[15];
  const float* be0 = (const float*)d_in[16];
  const float* g1  = (const float*)d_in[17];
  const float* be1 = (const float*)d_in[18];
  float* out = (float*)d_out;

  const int N = N_NODES, E = N_EDGES, H = H_HEADS, D = D_HID;
  const int C = H * D;  // 384

  // ---- workspace carve ----
  char* p = (char*)d_ws;
  auto take = [&](size_t bytes) {
    char* r = p;
    p += (bytes + 255) & ~(size_t)255;
    return r;
  };
  bf16*   f_buf   = (bf16*) take((size_t)N * C * sizeof(bf16));
  float*  hbuf    = (float*)take((size_t)N * C * sizeof(float));
  bf16*   abuf    = (bf16*) take((size_t)N * C * sizeof(bf16));
  float*  elbuf   = (float*)take((size_t)N * 4 * sizeof(float));
  float*  er      = (float*)take((size_t)N * H * sizeof(float));
  float*  bnbuf   = (float*)take((size_t)2 * C * sizeof(float));  // sum | sumsq
  bf16*   WT0     = (bf16*) take((size_t)C * F_IN * sizeof(bf16));
  bf16*   WT1     = (bf16*) take((size_t)C * C * sizeof(bf16));
  bf16*   WT2     = (bf16*) take((size_t)64 * C * sizeof(bf16));
  float*  alp2    = (float*)take(64 * sizeof(float));
  float*  arp2    = (float*)take(64 * sizeof(float));
  int*    cnt     = (int*)take((size_t)2 * N * sizeof(int));      // hist | fill
  int*    row_ptr = (int*)take((size_t)(N + 1) * sizeof(int));
  int*    csr_src = (int*)take((size_t)E * sizeof(int));
  float*  bnsum = bnbuf, *bnsq = bnbuf + C;
  int*    fill  = cnt + N;

  // ---- prep (cast, WT builds, pads, zeroing) + CSR build ----
  prep_kernel<<<cdiv(N * F_IN, 256), 256, 0, stream>>>(x, abuf, W0, W1, W2, WT0, WT1, WT2,
                                                       al2, ar2, alp2, arp2, cnt, elbuf, er);
  hist_kernel<<<cdiv(E, 256), 256, 0, stream>>>(dst, cnt, E);
  scan_kernel<<<1, 256, 0, stream>>>(cnt, row_ptr, N, E);
  scatter_kernel<<<cdiv(E, 256), 256, 0, stream>>>(src, dst, row_ptr, fill, csr_src, E);

  // ================= layer 0 =================
  gemm_mfma<<<dim3(C / 64, cdiv(N, 64)), 256, 0, stream>>>(
      (const short*)abuf, (const short*)WT0, f_buf, al0, ar0, elbuf, er, N, F_IN, C, 4, 3);
  aggr_fused_kernel<H_HEADS, D_HID><<<cdiv(N * 64, 256), 256, 0, stream>>>(
      row_ptr, csr_src, (const float4*)elbuf, er, f_buf, hbuf, bnbuf, N);
  bn_stats_kernel<<<256, C, 0, stream>>>(hbuf, bnsum, bnsq, N, C);
  bn_apply_kernel<<<cdiv(N * C, 256), 256, 0, stream>>>(hbuf, bnsum, bnsq, g0, be0, abuf,
                                                        elbuf, er, N, C);

  // ================= layer 1 =================
  gemm_mfma<<<dim3(C / 64, cdiv(N, 64)), 256, 0, stream>>>(
      (const short*)abuf, (const short*)WT1, f_buf, al1, ar1, elbuf, er, N, C, C, 4, 3);
  aggr_fused_kernel<H_HEADS, D_HID><<<cdiv(N * 64, 256), 256, 0, stream>>>(
      row_ptr, csr_src, (const float4*)elbuf, er, f_buf, hbuf, bnbuf, N);
  bn_stats_kernel<<<256, C, 0, stream>>>(hbuf, bnsum, bnsq, N, C);
  bn_apply_kernel<<<cdiv(N * C, 256), 256, 0, stream>>>(hbuf, bnsum, bnsq, g1, be1, abuf,
                                                        elbuf, er, N, C);

  // ================= layer 2 (H=1, D=40, bias fused, direct to out) =========
  gemm_mfma<<<dim3(1, cdiv(N, 64)), 256, 0, stream>>>(
      (const short*)abuf, (const short*)WT2, f_buf, alp2, arp2, elbuf, er, N, C, F_OUT, 1, 1);
  aggr_out_kernel<<<cdiv(N * 64, 256), 256, 0, stream>>>(
      row_ptr, csr_src, elbuf, er, f_buf, b2, out, N);
}